// Round 18
// baseline (360.526 us; speedup 1.0000x reference)
//
#include <hip/hip_runtime.h>
#include <hip/hip_fp16.h>

#define N_NODES 100000
#define N_EDGES 400000
#define N_GRAPHS 5000
#define NPG 20
#define SCAN_NB 256
#define SCAN_CHUNK ((N_NODES + SCAN_NB - 1) / SCAN_NB)  // 391
#define TAB_STRIDE (256 * 128 + 128)  // halves: T12[256][128] + v[128]
#define F1 8192   // ushorts per K=64 frag array (1024 frags * 8, fp16)
#define F2 16384  // ushorts per K=128 frag array (2048 frags * 8, fp16)
#define NB_ENC ((N_NODES + 255) / 256)   // 391
#define NB_HIST ((N_EDGES + 255) / 256)  // 1563

typedef __attribute__((ext_vector_type(8))) _Float16 f16x8;
typedef __attribute__((ext_vector_type(2))) _Float16 h2;
typedef __attribute__((ext_vector_type(4))) float f32x4;

// ---------------- fused prologue: encode_nodes | hist | tabs | prep ---------
__global__ __launch_bounds__(256) void k_prologue(
    const float* __restrict__ x, const float* __restrict__ atom_emb,
    const float* __restrict__ bool_emb, const float* __restrict__ Wn,
    const float* __restrict__ bn, __half* __restrict__ h0,
    const int* __restrict__ dst, int* __restrict__ cnt,
    const float* __restrict__ Wedge1, const float* __restrict__ Wedge2,
    const float* __restrict__ bond_emb, const float* __restrict__ We,
    const float* __restrict__ be, __half* __restrict__ tabs,
    const float* __restrict__ Wl1, const float* __restrict__ Wr1,
    const float* __restrict__ Wl2, const float* __restrict__ Wr2,
    unsigned short* __restrict__ fr) {
  int b = blockIdx.x, tid = threadIdx.x;
  if (b < NB_ENC) {
    // ---- node encoder: h0[N,64] fp16 (cols 52..63 zero) ----
    int n = b * 256 + tid;
    if (n >= N_NODES) return;
    const float* xr = x + (size_t)n * 14;
    __half* h = h0 + (size_t)n * 64;
    int ai = (int)xr[0];
    #pragma unroll
    for (int j = 0; j < 16; j++) h[j] = __float2half(atom_emb[ai * 16 + j]);
    float xc[10];
    #pragma unroll
    for (int k = 0; k < 10; k++) xc[k] = xr[1 + k];
    #pragma unroll
    for (int c = 0; c < 30; c++) {
      float s = bn[c];
      #pragma unroll
      for (int k = 0; k < 10; k++) s += xc[k] * Wn[k * 30 + c];
      h[16 + c] = __float2half(s);
    }
    #pragma unroll
    for (int t = 0; t < 3; t++) {
      int bb = (int)xr[11 + t];
      h[46 + 2 * t]     = __float2half(bool_emb[2 * bb]);
      h[46 + 2 * t + 1] = __float2half(bool_emb[2 * bb + 1]);
    }
    #pragma unroll
    for (int j = 52; j < 64; j++) h[j] = __float2half(0.0f);
  } else if (b < NB_ENC + NB_HIST) {
    // ---- in-degree histogram ----
    int e = (b - NB_ENC) * 256 + tid;
    if (e >= N_EDGES) return;
    atomicAdd(cnt + dst[e], 1);
  } else if (b == NB_ENC + NB_HIST) {
    // ---- fused logit table (fp16): T12[combo*32+bi], v; rows 22..31 = 0 ----
    int s = tid >> 7, c = tid & 127;
    const float* W = s ? Wedge2 : Wedge1;
    __half* T12 = tabs + (size_t)s * TAB_STRIDE;
    __half* v   = T12 + 256 * 128;
    float w8 = W[8 * 128 + c], w9 = W[9 * 128 + c];
    v[c] = __float2half(We[0] * w8 + We[1] * w9);
    float cst = be[0] * w8 + be[1] * w9;
    float bond[22];
    for (int bb = 0; bb < 22; bb++) {
      float acc = 0.f;
      #pragma unroll
      for (int k = 0; k < 8; k++) acc += bond_emb[bb * 8 + k] * W[k * 128 + c];
      bond[bb] = acc;
    }
    for (int combo = 0; combo < 8; combo++) {
      float t2 = cst;
      #pragma unroll
      for (int tt = 0; tt < 3; tt++) {
        int bt = (combo >> tt) & 1;
        t2 += bool_emb[bt * 2 + 0] * W[(10 + 2 * tt + 0) * 128 + c];
        t2 += bool_emb[bt * 2 + 1] * W[(10 + 2 * tt + 1) * 128 + c];
      }
      for (int bb = 0; bb < 22; bb++)
        T12[(combo * 32 + bb) * 128 + c] = __float2half(bond[bb] + t2);
      for (int bb = 22; bb < 32; bb++)   // incl. row 255 = zero (invalid slots)
        T12[(combo * 32 + bb) * 128 + c] = __float2half(0.f);
    }
  } else {
    // ---- W -> MFMA B-fragment prep (fp16, 8 halves = 16 B per frag) ----
    int g = (b - (NB_ENC + NB_HIST + 1)) * 256 + tid;
    const float* W; int K; unsigned short* base; int fl;
    if (g < 1024)      { W = Wl1; K = 52;  base = fr;               fl = g; }
    else if (g < 2048) { W = Wr1; K = 52;  base = fr + F1;          fl = g - 1024; }
    else if (g < 4096) { W = Wl2; K = 128; base = fr + 2 * F1;      fl = g - 2048; }
    else if (g < 6144) { W = Wr2; K = 128; base = fr + 2 * F1 + F2; fl = g - 4096; }
    else return;
    int l = fl & 63, ctn = fl >> 6;
    int tn = ctn & 7, c = ctn >> 3;
    int n = tn * 16 + (l & 15);
    int kb = c * 32 + (l >> 4) * 8;
    unsigned h8[8];
    #pragma unroll
    for (int j = 0; j < 8; j++) {
      int k = kb + j;
      float v = (k < K) ? W[(size_t)k * 128 + n] : 0.f;
      __half hv = __float2half(v);
      h8[j] = (unsigned)*(unsigned short*)&hv;
    }
    uint4 hv4 = make_uint4(h8[0] | (h8[1] << 16), h8[2] | (h8[3] << 16),
                           h8[4] | (h8[5] << 16), h8[6] | (h8[7] << 16));
    *(uint4*)(base + (size_t)fl * 8) = hv4;
  }
}

// ---------------- hierarchical scan over (cnt[n]+1), 3 phases ---------------
__global__ __launch_bounds__(256) void k_scan1(const int* __restrict__ cnt,
                                               int* __restrict__ bsum) {
  __shared__ int red[256];
  int b = blockIdx.x, t = threadIdx.x;
  int beg = b * SCAN_CHUNK;
  int end = beg + SCAN_CHUNK; if (end > N_NODES) end = N_NODES;
  int s = 0;
  for (int i = beg + t; i < end; i += 256) s += cnt[i] + 1;
  red[t] = s;
  __syncthreads();
  for (int off = 128; off > 0; off >>= 1) {
    if (t < off) red[t] += red[t + off];
    __syncthreads();
  }
  if (t == 0) bsum[b] = red[0];
}

__global__ __launch_bounds__(256) void k_scan2(int* __restrict__ bsum) {
  __shared__ int sh[256];
  int t = threadIdx.x;
  sh[t] = bsum[t];
  __syncthreads();
  for (int off = 1; off < 256; off <<= 1) {
    int v = (t >= off) ? sh[t - off] : 0;
    __syncthreads();
    sh[t] += v;
    __syncthreads();
  }
  bsum[t] = (t > 0) ? sh[t - 1] : 0;  // exclusive
}

__global__ __launch_bounds__(256) void k_scan3(const int* __restrict__ cnt,
                                               const int* __restrict__ bsum,
                                               int* __restrict__ indptr,
                                               int* __restrict__ cursor) {
  __shared__ int sh[256];
  __shared__ int carry;
  int b = blockIdx.x, t = threadIdx.x;
  int beg = b * SCAN_CHUNK;
  int end = beg + SCAN_CHUNK; if (end > N_NODES) end = N_NODES;
  if (t == 0) carry = bsum[b];
  __syncthreads();
  for (int base = beg; base < end; base += 256) {
    int i = base + t;
    int v = (i < end) ? cnt[i] + 1 : 0;
    sh[t] = v;
    __syncthreads();
    for (int off = 1; off < 256; off <<= 1) {
      int u = (t >= off) ? sh[t - off] : 0;
      __syncthreads();
      sh[t] += u;
      __syncthreads();
    }
    int excl = sh[t] - v;
    if (i < end) {
      int val = carry + excl;
      indptr[i] = val;
      cursor[i] = val;
    }
    __syncthreads();
    if (t == 255) carry += sh[255];
    __syncthreads();
  }
  if (b == 0 && t == 0) indptr[N_NODES] = N_EDGES + N_NODES;
}

// ---------------- CSR fill: ordinary edges into slots [beg, end-1) ----------
__global__ void k_fill(const int* __restrict__ srcA,
                       const int* __restrict__ dst,
                       const float* __restrict__ eattr,
                       int* __restrict__ cursor,
                       int4* __restrict__ scode) {
  int e = blockIdx.x * blockDim.x + threadIdx.x;
  if (e >= N_EDGES) return;
  const float* r = eattr + (size_t)e * 5;
  int bi = (int)r[0];
  float ec = r[1];
  int combo = (int)r[2] + 2 * (int)r[3] + 4 * (int)r[4];
  int meta = bi | (combo << 5);
  int d = dst[e];
  int p = atomicAdd(&cursor[d], 1);
  scode[p] = make_int4(srcA[e], meta, __float_as_int(ec), 0);
}

// ---------------- MFMA dual GEMM, M=16/wave, 64k-chunk LDS, LDS epilogue ----
// Stage 64 k's at a time (32 KB: L+R, 16 KB each); epilogue transposes acc
// through a per-wave 4 KB region of the dead stage buffer -> fully coalesced
// dwordx4 stores (vs 64 scalar 2B stores).
template <int KPAD>
__global__ __launch_bounds__(256, 4) void k_gemm2m(const __half* __restrict__ A,
                                                   const unsigned short* __restrict__ WfL,
                                                   const unsigned short* __restrict__ WfR,
                                                   const float* __restrict__ bl_,
                                                   const float* __restrict__ br_,
                                                   __half* __restrict__ outl,
                                                   __half* __restrict__ outr) {
  __shared__ unsigned short Bs[2][8192];  // L, R (16 KB each, 64 k's)
  const int tid = threadIdx.x;
  const int wv = tid >> 6, lane = tid & 63;
  const int tw = blockIdx.x * 4 + wv;
  const bool active = (tw < N_NODES / 16);  // tail waves stay for barriers
  const int ml = lane & 15, q = lane >> 4;
  const int m0 = active ? tw * 16 : 0;
  f32x4 accL[8], accR[8];
  #pragma unroll
  for (int t = 0; t < 8; t++) {
    accL[t] = (f32x4){0.f, 0.f, 0.f, 0.f};
    accR[t] = (f32x4){0.f, 0.f, 0.f, 0.f};
  }
  const _Float16* ar0 = (const _Float16*)A + (size_t)(m0 + ml) * KPAD + q * 8;
  constexpr int NC2 = KPAD / 64;
  for (int c2 = 0; c2 < NC2; c2++) {
    // stage 64-k chunk: 1024 frags (16 B each) per W = 16 KB per W
    #pragma unroll
    for (int i0 = 0; i0 < 1024; i0 += 256) {
      int i = i0 + tid;
      size_t g = ((size_t)c2 * 1024 + i) * 8;
      *(uint4*)(&Bs[0][i * 8]) = *(const uint4*)(WfL + g);
      *(uint4*)(&Bs[1][i * 8]) = *(const uint4*)(WfR + g);
    }
    __syncthreads();
    #pragma unroll
    for (int sub = 0; sub < 2; sub++) {
      f16x8 a = *(const f16x8*)(ar0 + c2 * 64 + sub * 32);
      #pragma unroll
      for (int t = 0; t < 8; t++) {
        int idx = (sub * 512 + t * 64 + lane) * 8;
        f16x8 bL = *(const f16x8*)(&Bs[0][idx]);
        f16x8 bR = *(const f16x8*)(&Bs[1][idx]);
        accL[t] = __builtin_amdgcn_mfma_f32_16x16x32_f16(a, bL, accL[t], 0, 0, 0);
        accR[t] = __builtin_amdgcn_mfma_f32_16x16x32_f16(a, bR, accR[t], 0, 0, 0);
      }
    }
    __syncthreads();
  }
  // one barrier so all waves finish reading Bs before we reuse it as scratch
  __syncthreads();
  if (!active) return;
  // epilogue: acc (C/D layout col=lane&15, row=quad*4+reg) -> per-wave 4 KB
  // LDS transpose -> coalesced 16 B/lane stores.
  __half* eb = (__half*)&Bs[0][0] + wv * 2048;  // 16 rows x 128 cols fp16
  const int srow = q * 4;           // rows this lane writes
  const int rrow0 = lane >> 4;      // read-back: row p*4 + lane/16
  const int rcol = (lane & 15) * 8; // read-back col
  // ---- L ----
  #pragma unroll
  for (int t = 0; t < 8; t++) {
    int n = t * 16 + ml;
    float bL = bl_[n];
    #pragma unroll
    for (int r = 0; r < 4; r++)
      eb[(srow + r) * 128 + n] = __float2half(accL[t][r] + bL);
  }
  #pragma unroll
  for (int pp = 0; pp < 4; pp++) {
    uint4 v = *(const uint4*)(eb + pp * 512 + lane * 8);
    *(uint4*)(outl + (size_t)(m0 + pp * 4 + rrow0) * 128 + rcol) = v;
  }
  // ---- R (reuse same region; within-wave LDS ordering is tracked) ----
  #pragma unroll
  for (int t = 0; t < 8; t++) {
    int n = t * 16 + ml;
    float bR = br_[n];
    #pragma unroll
    for (int r = 0; r < 4; r++)
      eb[(srow + r) * 128 + n] = __float2half(accR[t][r] + bR);
  }
  #pragma unroll
  for (int pp = 0; pp < 4; pp++) {
    uint4 v = *(const uint4*)(eb + pp * 512 + lane * 8);
    *(uint4*)(outr + (size_t)(m0 + pp * 4 + rrow0) * 128 + rcol) = v;
  }
}

// ---------------- GATv2 edge pass: 16 lanes/node (4 nodes/wave) -------------
// 8 ch/lane => 16 B/lane gathers (dwordx4, 4 rows per instruction);
// 4-step quarter-wave reductions. T12 row 255 = 0 so invalid lock-step slots
// contribute el=0 with no masking. Plain-sum softmax (logits O(0.3)).
// Never use unvalidated scode data as an address. Grid sized for ONE pass.
__global__ __launch_bounds__(256) void k_gat(const __half* __restrict__ xl,
                                             const __half* __restrict__ xr,
                                             const int* __restrict__ indptr,
                                             const int4* __restrict__ scode,
                                             const __half* __restrict__ tabs,
                                             const float* __restrict__ att,
                                             const float* __restrict__ bias,
                                             __half* __restrict__ hout) {
  int wid = (blockIdx.x * 256 + threadIdx.x) >> 6;
  int nw = (gridDim.x * 256) >> 6;
  int lane = threadIdx.x & 63;
  int q4 = lane >> 4;            // quarter (node within wave)
  int c = (lane & 15) * 8;       // 8 channels per lane
  const __half* T12 = tabs;      // 256 x 128 fp16
  uint4 vu = *(const uint4*)(tabs + 256 * 128 + c);
  h2 v4[4] = {*reinterpret_cast<h2*>(&vu.x), *reinterpret_cast<h2*>(&vu.y),
              *reinterpret_cast<h2*>(&vu.z), *reinterpret_cast<h2*>(&vu.w)};
  float4 af0 = *(const float4*)(att + c);
  float4 af1 = *(const float4*)(att + c + 4);
  h2 a4[4] = {{(_Float16)af0.x, (_Float16)af0.y}, {(_Float16)af0.z, (_Float16)af0.w},
              {(_Float16)af1.x, (_Float16)af1.y}, {(_Float16)af1.z, (_Float16)af1.w}};
  float bb[8];
  {
    float4 b0 = *(const float4*)(bias + c);
    float4 b1 = *(const float4*)(bias + c + 4);
    bb[0] = b0.x; bb[1] = b0.y; bb[2] = b0.z; bb[3] = b0.w;
    bb[4] = b1.x; bb[5] = b1.y; bb[6] = b1.z; bb[7] = b1.w;
  }
  const h2 z2 = {(_Float16)0.f, (_Float16)0.f};
  const h2 k2 = {(_Float16)0.2f, (_Float16)0.2f};
  wid = __builtin_amdgcn_readfirstlane(wid);
  for (int nb = wid * 4; nb < N_NODES; nb += nw * 4) {
    int n = nb + q4;  // N_NODES % 4 == 0 -> always valid
    int beg = indptr[n], end1 = indptr[n + 1] - 1;  // end1 = self-loop slot
    int last = (end1 > beg) ? end1 - 1 : beg;       // clamp (may be unwritten!)
    uint4 xru = *(const uint4*)(xr + (size_t)n * 128 + c);
    h2 xrv[4] = {*reinterpret_cast<h2*>(&xru.x), *reinterpret_cast<h2*>(&xru.y),
                 *reinterpret_cast<h2*>(&xru.z), *reinterpret_cast<h2*>(&xru.w)};
    float denom = 0.f;
    float acc[8] = {0.f, 0.f, 0.f, 0.f, 0.f, 0.f, 0.f, 0.f};
    h2 els[4] = {z2, z2, z2, z2};
    int my_it = (end1 - beg + 3) >> 2;
    int m1 = my_it, m2;
    m2 = __shfl_xor(m1, 16, 64); m1 = m1 > m2 ? m1 : m2;
    m2 = __shfl_xor(m1, 32, 64); m1 = m1 > m2 ? m1 : m2;
    int iters = m1;  // wave-uniform
    for (int it = 0; it < iters; it++) {
      int j = beg + it * 4;
      int4 sc4[4]; h2 xlv[4][4]; float tt[4];
      bool val[4];
      #pragma unroll
      for (int u = 0; u < 4; u++) {
        val[u] = (j + u < end1);  // uniform within quarter
        int jj = val[u] ? j + u : last;
        sc4[u] = scode[jj];
      }
      #pragma unroll
      for (int u = 0; u < 4; u++) {
        int s = val[u] ? sc4[u].x : n;  // NEVER use poison as an address
        uint4 lv = *(const uint4*)(xl + (size_t)s * 128 + c);
        xlv[u][0] = *reinterpret_cast<h2*>(&lv.x);
        xlv[u][1] = *reinterpret_cast<h2*>(&lv.y);
        xlv[u][2] = *reinterpret_cast<h2*>(&lv.z);
        xlv[u][3] = *reinterpret_cast<h2*>(&lv.w);
      }
      #pragma unroll
      for (int u = 0; u < 4; u++) {
        int meta = val[u] ? (sc4[u].y & 255) : 255;  // row 255 = zeros
        float ec = val[u] ? __int_as_float(sc4[u].z) : 0.f;
        uint4 tv = *(const uint4*)(T12 + (size_t)meta * 128 + c);
        h2 t4[4] = {*reinterpret_cast<h2*>(&tv.x), *reinterpret_cast<h2*>(&tv.y),
                    *reinterpret_cast<h2*>(&tv.z), *reinterpret_cast<h2*>(&tv.w)};
        _Float16 eh = (_Float16)ec;
        h2 eh2 = {eh, eh};
        h2 d = z2;
        #pragma unroll
        for (int k = 0; k < 4; k++) {
          h2 el = eh2 * v4[k] + t4[k];
          h2 m = xlv[u][k] + xrv[k] + el;
          h2 l = __builtin_elementwise_max(m, z2) + k2 * __builtin_elementwise_min(m, z2);
          d += l * a4[k];
          els[k] += el;  // el=0 for invalid slots — no mask
        }
        tt[u] = (float)d[0] + (float)d[1];
      }
      // 4 independent quarter-wave reduction chains, 4 steps
      #pragma unroll
      for (int off = 1; off < 16; off <<= 1) {
        tt[0] += __shfl_xor(tt[0], off, 64);
        tt[1] += __shfl_xor(tt[1], off, 64);
        tt[2] += __shfl_xor(tt[2], off, 64);
        tt[3] += __shfl_xor(tt[3], off, 64);
      }
      #pragma unroll
      for (int u = 0; u < 4; u++) {
        float ex = val[u] ? __expf(tt[u]) : 0.f;
        denom += ex;
        #pragma unroll
        for (int k = 0; k < 4; k++) {
          acc[2 * k]     += ex * (float)xlv[u][k][0];
          acc[2 * k + 1] += ex * (float)xlv[u][k][1];
        }
      }
    }
    // self-loop (always present, processed last) — fp32 path
    int cntn = end1 - beg;
    float inv_cnt = 1.0f / (float)(cntn > 0 ? cntn : 1);
    uint4 xnu = *(const uint4*)(xl + (size_t)n * 128 + c);
    h2 xn[4] = {*reinterpret_cast<h2*>(&xnu.x), *reinterpret_cast<h2*>(&xnu.y),
                *reinterpret_cast<h2*>(&xnu.z), *reinterpret_cast<h2*>(&xnu.w)};
    float afv[8] = {af0.x, af0.y, af0.z, af0.w, af1.x, af1.y, af1.z, af1.w};
    float ts = 0.f;
    float xnf[8];
    #pragma unroll
    for (int k = 0; k < 4; k++) {
      #pragma unroll
      for (int hh = 0; hh < 2; hh++) {
        int i = 2 * k + hh;
        xnf[i] = (float)xn[k][hh];
        float m = xnf[i] + (float)xrv[k][hh] + (float)els[k][hh] * inv_cnt;
        float l = m > 0.f ? m : 0.2f * m;
        ts += l * afv[i];
      }
    }
    #pragma unroll
    for (int off = 1; off < 16; off <<= 1) ts += __shfl_xor(ts, off, 64);
    float ex = __expf(ts);
    denom += ex;
    #pragma unroll
    for (int i = 0; i < 8; i++) acc[i] += ex * xnf[i];
    float invd = 1.0f / denom;
    h2 p[4];
    #pragma unroll
    for (int k = 0; k < 4; k++) {
      float o0 = acc[2 * k] * invd + bb[2 * k];
      float o1 = acc[2 * k + 1] * invd + bb[2 * k + 1];
      o0 = o0 > 0.f ? o0 : 0.f;
      o1 = o1 > 0.f ? o1 : 0.f;
      p[k] = (h2){(_Float16)o0, (_Float16)o1};
    }
    uint4 st = make_uint4(*reinterpret_cast<unsigned*>(&p[0]),
                          *reinterpret_cast<unsigned*>(&p[1]),
                          *reinterpret_cast<unsigned*>(&p[2]),
                          *reinterpret_cast<unsigned*>(&p[3]));
    *(uint4*)(hout + (size_t)n * 128 + c) = st;
  }
}

// ---------------- readout: global max pool over 20 contiguous nodes --------
__global__ void k_readout(const __half* __restrict__ h, float* __restrict__ out) {
  int wid = (blockIdx.x * blockDim.x + threadIdx.x) >> 6;
  int lane = threadIdx.x & 63;
  if (wid >= N_GRAPHS) return;
  int c = lane * 2;
  float m0 = -1e30f, m1 = -1e30f;
  for (int i = 0; i < NPG; i++) {
    unsigned v = *(const unsigned*)(h + ((size_t)(wid * NPG + i)) * 128 + c);
    h2 f = *reinterpret_cast<h2*>(&v);
    m0 = fmaxf(m0, (float)f[0]);
    m1 = fmaxf(m1, (float)f[1]);
  }
  float2 o; o.x = m0; o.y = m1;
  *(float2*)(out + (size_t)wid * 128 + c) = o;
}

extern "C" void kernel_launch(void* const* d_in, const int* in_sizes, int n_in,
                              void* d_out, int out_size, void* d_ws, size_t ws_size,
                              hipStream_t stream) {
  (void)in_sizes; (void)n_in; (void)out_size; (void)ws_size;
  const float* x        = (const float*)d_in[0];
  const int*   eindex   = (const int*)d_in[1];
  const float* eattr    = (const float*)d_in[2];
  const float* atom_emb = (const float*)d_in[4];
  const float* bond_emb = (const float*)d_in[5];
  const float* bool_emb = (const float*)d_in[6];
  const float* Wn   = (const float*)d_in[7];
  const float* bn   = (const float*)d_in[8];
  const float* We   = (const float*)d_in[9];
  const float* be   = (const float*)d_in[10];
  const float* Wl1  = (const float*)d_in[11];
  const float* bl1  = (const float*)d_in[12];
  const float* Wr1  = (const float*)d_in[13];
  const float* br1  = (const float*)d_in[14];
  const float* Wedge1 = (const float*)d_in[15];
  const float* att1 = (const float*)d_in[16];
  const float* bias1 = (const float*)d_in[17];
  const float* Wl2  = (const float*)d_in[18];
  const float* bl2  = (const float*)d_in[19];
  const float* Wr2  = (const float*)d_in[20];
  const float* br2  = (const float*)d_in[21];
  const float* Wedge2 = (const float*)d_in[22];
  const float* att2 = (const float*)d_in[23];
  const float* bias2 = (const float*)d_in[24];

  const int* srcA = eindex;
  const int* dstA = eindex + N_EDGES;

  char* p = (char*)d_ws;
  auto alloc = [&](size_t bytes) {
    char* r = p;
    p += (bytes + 255) & ~(size_t)255;
    return r;
  };
  __half* h0     = (__half*)alloc((size_t)N_NODES * 64 * 2);
  __half* h      = (__half*)alloc((size_t)N_NODES * 128 * 2);
  __half* xl     = (__half*)alloc((size_t)N_NODES * 128 * 2);
  __half* xrb    = (__half*)alloc((size_t)N_NODES * 128 * 2);
  int*    cnt    = (int*)alloc((size_t)N_NODES * 4);
  int*    indptr = (int*)alloc((size_t)(N_NODES + 1) * 4);
  int*    cursor = (int*)alloc((size_t)N_NODES * 4);
  int4*   scode  = (int4*)alloc((size_t)(N_EDGES + N_NODES) * 16);
  __half* tabs   = (__half*)alloc((size_t)2 * TAB_STRIDE * 2);
  unsigned short* wfrag = (unsigned short*)alloc((size_t)(2 * F1 + 2 * F2) * 2);
  int*    bsum   = (int*)alloc((size_t)SCAN_NB * 4);

  (void)hipMemsetAsync(cnt, 0, (size_t)N_NODES * 4, stream);

  // fused prologue: encode | hist | tabs | prep
  k_prologue<<<NB_ENC + NB_HIST + 1 + 24, 256, 0, stream>>>(
      x, atom_emb, bool_emb, Wn, bn, h0, dstA, cnt,
      Wedge1, Wedge2, bond_emb, We, be, tabs,
      Wl1, Wr1, Wl2, Wr2, wfrag);
  k_scan1<<<SCAN_NB, 256, 0, stream>>>(cnt, bsum);
  k_scan2<<<1, 256, 0, stream>>>(bsum);
  k_scan3<<<SCAN_NB, 256, 0, stream>>>(cnt, bsum, indptr, cursor);
  k_fill<<<(N_EDGES + 255) / 256, 256, 0, stream>>>(srcA, dstA, eattr, cursor, scode);

  const unsigned short* f_l1 = wfrag;
  const unsigned short* f_r1 = wfrag + F1;
  const unsigned short* f_l2 = wfrag + 2 * F1;
  const unsigned short* f_r2 = wfrag + 2 * F1 + F2;

  const int GB2 = (N_NODES / 16 + 3) / 4;   // 1563 blocks of 4 waves
  const int GGAT = (N_NODES / 16 + 15) / 16 * 4;  // 6250 blocks: one 4-node pass/wave

  // layer 1 (K=52 zero-padded to 64)
  k_gemm2m<64><<<GB2, 256, 0, stream>>>(h0, f_l1, f_r1, bl1, br1, xl, xrb);
  k_gat<<<GGAT, 256, 0, stream>>>(xl, xrb, indptr, scode, tabs, att1, bias1, h);

  // layer 2 (K=128)
  k_gemm2m<128><<<GB2, 256, 0, stream>>>(h, f_l2, f_r2, bl2, br2, xl, xrb);
  k_gat<<<GGAT, 256, 0, stream>>>(xl, xrb, indptr, scode, tabs + TAB_STRIDE, att2, bias2, h);

  // layer 3 (shared weights with layer 2)
  k_gemm2m<128><<<GB2, 256, 0, stream>>>(h, f_l2, f_r2, bl2, br2, xl, xrb);
  k_gat<<<GGAT, 256, 0, stream>>>(xl, xrb, indptr, scode, tabs + TAB_STRIDE, att2, bias2, h);

  k_readout<<<(N_GRAPHS * 64 + 255) / 256, 256, 0, stream>>>(h, (float*)d_out);
}

// Round 19
// 357.309 us; speedup vs baseline: 1.0090x; 1.0090x over previous
//
#include <hip/hip_runtime.h>
#include <hip/hip_fp16.h>

#define N_NODES 100000
#define N_EDGES 400000
#define N_GRAPHS 5000
#define NPG 20
#define SCAN_NB 256
#define SCAN_CHUNK ((N_NODES + SCAN_NB - 1) / SCAN_NB)  // 391
#define TAB_STRIDE (256 * 128 + 128)  // halves: T12[256][128] + v[128]
#define F1 8192   // ushorts per K=64 frag array (1024 frags * 8, fp16)
#define F2 16384  // ushorts per K=128 frag array (2048 frags * 8, fp16)
#define NB_ENC ((N_NODES + 255) / 256)   // 391
#define NB_HIST ((N_EDGES + 255) / 256)  // 1563

typedef __attribute__((ext_vector_type(8))) _Float16 f16x8;
typedef __attribute__((ext_vector_type(2))) _Float16 h2;
typedef __attribute__((ext_vector_type(4))) float f32x4;

// ---------------- fused prologue: encode_nodes | hist | tabs | prep ---------
__global__ __launch_bounds__(256) void k_prologue(
    const float* __restrict__ x, const float* __restrict__ atom_emb,
    const float* __restrict__ bool_emb, const float* __restrict__ Wn,
    const float* __restrict__ bn, __half* __restrict__ h0,
    const int* __restrict__ dst, int* __restrict__ cnt,
    const float* __restrict__ Wedge1, const float* __restrict__ Wedge2,
    const float* __restrict__ bond_emb, const float* __restrict__ We,
    const float* __restrict__ be, __half* __restrict__ tabs,
    const float* __restrict__ Wl1, const float* __restrict__ Wr1,
    const float* __restrict__ Wl2, const float* __restrict__ Wr2,
    unsigned short* __restrict__ fr) {
  int b = blockIdx.x, tid = threadIdx.x;
  if (b < NB_ENC) {
    // ---- node encoder: h0[N,64] fp16 (cols 52..63 zero) ----
    int n = b * 256 + tid;
    if (n >= N_NODES) return;
    const float* xr = x + (size_t)n * 14;
    __half* h = h0 + (size_t)n * 64;
    int ai = (int)xr[0];
    #pragma unroll
    for (int j = 0; j < 16; j++) h[j] = __float2half(atom_emb[ai * 16 + j]);
    float xc[10];
    #pragma unroll
    for (int k = 0; k < 10; k++) xc[k] = xr[1 + k];
    #pragma unroll
    for (int c = 0; c < 30; c++) {
      float s = bn[c];
      #pragma unroll
      for (int k = 0; k < 10; k++) s += xc[k] * Wn[k * 30 + c];
      h[16 + c] = __float2half(s);
    }
    #pragma unroll
    for (int t = 0; t < 3; t++) {
      int bb = (int)xr[11 + t];
      h[46 + 2 * t]     = __float2half(bool_emb[2 * bb]);
      h[46 + 2 * t + 1] = __float2half(bool_emb[2 * bb + 1]);
    }
    #pragma unroll
    for (int j = 52; j < 64; j++) h[j] = __float2half(0.0f);
  } else if (b < NB_ENC + NB_HIST) {
    // ---- in-degree histogram ----
    int e = (b - NB_ENC) * 256 + tid;
    if (e >= N_EDGES) return;
    atomicAdd(cnt + dst[e], 1);
  } else if (b == NB_ENC + NB_HIST) {
    // ---- fused logit table (fp16): T12[combo*32+bi], v; rows 22..31 = 0 ----
    int s = tid >> 7, c = tid & 127;
    const float* W = s ? Wedge2 : Wedge1;
    __half* T12 = tabs + (size_t)s * TAB_STRIDE;
    __half* v   = T12 + 256 * 128;
    float w8 = W[8 * 128 + c], w9 = W[9 * 128 + c];
    v[c] = __float2half(We[0] * w8 + We[1] * w9);
    float cst = be[0] * w8 + be[1] * w9;
    float bond[22];
    for (int bb = 0; bb < 22; bb++) {
      float acc = 0.f;
      #pragma unroll
      for (int k = 0; k < 8; k++) acc += bond_emb[bb * 8 + k] * W[k * 128 + c];
      bond[bb] = acc;
    }
    for (int combo = 0; combo < 8; combo++) {
      float t2 = cst;
      #pragma unroll
      for (int tt = 0; tt < 3; tt++) {
        int bt = (combo >> tt) & 1;
        t2 += bool_emb[bt * 2 + 0] * W[(10 + 2 * tt + 0) * 128 + c];
        t2 += bool_emb[bt * 2 + 1] * W[(10 + 2 * tt + 1) * 128 + c];
      }
      for (int bb = 0; bb < 22; bb++)
        T12[(combo * 32 + bb) * 128 + c] = __float2half(bond[bb] + t2);
      for (int bb = 22; bb < 32; bb++)   // incl. row 255 = zero (invalid slots)
        T12[(combo * 32 + bb) * 128 + c] = __float2half(0.f);
    }
  } else {
    // ---- W -> MFMA B-fragment prep (fp16, 8 halves = 16 B per frag) ----
    int g = (b - (NB_ENC + NB_HIST + 1)) * 256 + tid;
    const float* W; int K; unsigned short* base; int fl;
    if (g < 1024)      { W = Wl1; K = 52;  base = fr;               fl = g; }
    else if (g < 2048) { W = Wr1; K = 52;  base = fr + F1;          fl = g - 1024; }
    else if (g < 4096) { W = Wl2; K = 128; base = fr + 2 * F1;      fl = g - 2048; }
    else if (g < 6144) { W = Wr2; K = 128; base = fr + 2 * F1 + F2; fl = g - 4096; }
    else return;
    int l = fl & 63, ctn = fl >> 6;
    int tn = ctn & 7, c = ctn >> 3;
    int n = tn * 16 + (l & 15);
    int kb = c * 32 + (l >> 4) * 8;
    unsigned h8[8];
    #pragma unroll
    for (int j = 0; j < 8; j++) {
      int k = kb + j;
      float v = (k < K) ? W[(size_t)k * 128 + n] : 0.f;
      __half hv = __float2half(v);
      h8[j] = (unsigned)*(unsigned short*)&hv;
    }
    uint4 hv4 = make_uint4(h8[0] | (h8[1] << 16), h8[2] | (h8[3] << 16),
                           h8[4] | (h8[5] << 16), h8[6] | (h8[7] << 16));
    *(uint4*)(base + (size_t)fl * 8) = hv4;
  }
}

// ---------------- hierarchical scan over (cnt[n]+1), 3 phases ---------------
__global__ __launch_bounds__(256) void k_scan1(const int* __restrict__ cnt,
                                               int* __restrict__ bsum) {
  __shared__ int red[256];
  int b = blockIdx.x, t = threadIdx.x;
  int beg = b * SCAN_CHUNK;
  int end = beg + SCAN_CHUNK; if (end > N_NODES) end = N_NODES;
  int s = 0;
  for (int i = beg + t; i < end; i += 256) s += cnt[i] + 1;
  red[t] = s;
  __syncthreads();
  for (int off = 128; off > 0; off >>= 1) {
    if (t < off) red[t] += red[t + off];
    __syncthreads();
  }
  if (t == 0) bsum[b] = red[0];
}

__global__ __launch_bounds__(256) void k_scan2(int* __restrict__ bsum) {
  __shared__ int sh[256];
  int t = threadIdx.x;
  sh[t] = bsum[t];
  __syncthreads();
  for (int off = 1; off < 256; off <<= 1) {
    int v = (t >= off) ? sh[t - off] : 0;
    __syncthreads();
    sh[t] += v;
    __syncthreads();
  }
  bsum[t] = (t > 0) ? sh[t - 1] : 0;  // exclusive
}

__global__ __launch_bounds__(256) void k_scan3(const int* __restrict__ cnt,
                                               const int* __restrict__ bsum,
                                               int* __restrict__ indptr,
                                               int* __restrict__ cursor) {
  __shared__ int sh[256];
  __shared__ int carry;
  int b = blockIdx.x, t = threadIdx.x;
  int beg = b * SCAN_CHUNK;
  int end = beg + SCAN_CHUNK; if (end > N_NODES) end = N_NODES;
  if (t == 0) carry = bsum[b];
  __syncthreads();
  for (int base = beg; base < end; base += 256) {
    int i = base + t;
    int v = (i < end) ? cnt[i] + 1 : 0;
    sh[t] = v;
    __syncthreads();
    for (int off = 1; off < 256; off <<= 1) {
      int u = (t >= off) ? sh[t - off] : 0;
      __syncthreads();
      sh[t] += u;
      __syncthreads();
    }
    int excl = sh[t] - v;
    if (i < end) {
      int val = carry + excl;
      indptr[i] = val;
      cursor[i] = val;
    }
    __syncthreads();
    if (t == 255) carry += sh[255];
    __syncthreads();
  }
  if (b == 0 && t == 0) indptr[N_NODES] = N_EDGES + N_NODES;
}

// ---------------- CSR fill: ordinary edges into slots [beg, end-1) ----------
__global__ void k_fill(const int* __restrict__ srcA,
                       const int* __restrict__ dst,
                       const float* __restrict__ eattr,
                       int* __restrict__ cursor,
                       int4* __restrict__ scode) {
  int e = blockIdx.x * blockDim.x + threadIdx.x;
  if (e >= N_EDGES) return;
  const float* r = eattr + (size_t)e * 5;
  int bi = (int)r[0];
  float ec = r[1];
  int combo = (int)r[2] + 2 * (int)r[3] + 4 * (int)r[4];
  int meta = bi | (combo << 5);
  int d = dst[e];
  int p = atomicAdd(&cursor[d], 1);
  scode[p] = make_int4(srcA[e], meta, __float_as_int(ec), 0);
}

// ---------------- MFMA dual GEMM, M=16/wave, 64k-chunk LDS, LDS epilogue ----
template <int KPAD>
__global__ __launch_bounds__(256, 4) void k_gemm2m(const __half* __restrict__ A,
                                                   const unsigned short* __restrict__ WfL,
                                                   const unsigned short* __restrict__ WfR,
                                                   const float* __restrict__ bl_,
                                                   const float* __restrict__ br_,
                                                   __half* __restrict__ outl,
                                                   __half* __restrict__ outr) {
  __shared__ unsigned short Bs[2][8192];  // L, R (16 KB each, 64 k's)
  const int tid = threadIdx.x;
  const int wv = tid >> 6, lane = tid & 63;
  const int tw = blockIdx.x * 4 + wv;
  const bool active = (tw < N_NODES / 16);  // tail waves stay for barriers
  const int ml = lane & 15, q = lane >> 4;
  const int m0 = active ? tw * 16 : 0;
  f32x4 accL[8], accR[8];
  #pragma unroll
  for (int t = 0; t < 8; t++) {
    accL[t] = (f32x4){0.f, 0.f, 0.f, 0.f};
    accR[t] = (f32x4){0.f, 0.f, 0.f, 0.f};
  }
  const _Float16* ar0 = (const _Float16*)A + (size_t)(m0 + ml) * KPAD + q * 8;
  constexpr int NC2 = KPAD / 64;
  for (int c2 = 0; c2 < NC2; c2++) {
    // stage 64-k chunk: 1024 frags (16 B each) per W = 16 KB per W
    #pragma unroll
    for (int i0 = 0; i0 < 1024; i0 += 256) {
      int i = i0 + tid;
      size_t g = ((size_t)c2 * 1024 + i) * 8;
      *(uint4*)(&Bs[0][i * 8]) = *(const uint4*)(WfL + g);
      *(uint4*)(&Bs[1][i * 8]) = *(const uint4*)(WfR + g);
    }
    __syncthreads();
    #pragma unroll
    for (int sub = 0; sub < 2; sub++) {
      f16x8 a = *(const f16x8*)(ar0 + c2 * 64 + sub * 32);
      #pragma unroll
      for (int t = 0; t < 8; t++) {
        int idx = (sub * 512 + t * 64 + lane) * 8;
        f16x8 bL = *(const f16x8*)(&Bs[0][idx]);
        f16x8 bR = *(const f16x8*)(&Bs[1][idx]);
        accL[t] = __builtin_amdgcn_mfma_f32_16x16x32_f16(a, bL, accL[t], 0, 0, 0);
        accR[t] = __builtin_amdgcn_mfma_f32_16x16x32_f16(a, bR, accR[t], 0, 0, 0);
      }
    }
    __syncthreads();
  }
  // one barrier so all waves finish reading Bs before we reuse it as scratch
  __syncthreads();
  if (!active) return;
  // epilogue: acc (C/D layout col=lane&15, row=quad*4+reg) -> per-wave 4 KB
  // LDS transpose -> coalesced 16 B/lane stores.
  __half* eb = (__half*)&Bs[0][0] + wv * 2048;  // 16 rows x 128 cols fp16
  const int srow = q * 4;           // rows this lane writes
  const int rrow0 = lane >> 4;      // read-back: row p*4 + lane/16
  const int rcol = (lane & 15) * 8; // read-back col
  // ---- L ----
  #pragma unroll
  for (int t = 0; t < 8; t++) {
    int n = t * 16 + ml;
    float bL = bl_[n];
    #pragma unroll
    for (int r = 0; r < 4; r++)
      eb[(srow + r) * 128 + n] = __float2half(accL[t][r] + bL);
  }
  #pragma unroll
  for (int pp = 0; pp < 4; pp++) {
    uint4 v = *(const uint4*)(eb + pp * 512 + lane * 8);
    *(uint4*)(outl + (size_t)(m0 + pp * 4 + rrow0) * 128 + rcol) = v;
  }
  // ---- R (reuse same region; within-wave LDS ordering is tracked) ----
  #pragma unroll
  for (int t = 0; t < 8; t++) {
    int n = t * 16 + ml;
    float bR = br_[n];
    #pragma unroll
    for (int r = 0; r < 4; r++)
      eb[(srow + r) * 128 + n] = __float2half(accR[t][r] + bR);
  }
  #pragma unroll
  for (int pp = 0; pp < 4; pp++) {
    uint4 v = *(const uint4*)(eb + pp * 512 + lane * 8);
    *(uint4*)(outr + (size_t)(m0 + pp * 4 + rrow0) * 128 + rcol) = v;
  }
}

// ---------------- GATv2 edge pass: 16 lanes/node (4 nodes/wave) -------------
// 8 ch/lane => 16 B/lane gathers (dwordx4, 4 rows per instruction);
// 4-step quarter-wave reductions. T12 row 255 = 0 so invalid lock-step slots
// contribute el=0 with no masking. Plain-sum softmax (logits O(0.3)).
// Never use unvalidated scode data as an address.
// Grid: 2048 persistent blocks (grid-stride loop smooths degree imbalance —
// one-pass-per-wave grids measured WORSE: r18 52 vs 48 us).
__global__ __launch_bounds__(256) void k_gat(const __half* __restrict__ xl,
                                             const __half* __restrict__ xr,
                                             const int* __restrict__ indptr,
                                             const int4* __restrict__ scode,
                                             const __half* __restrict__ tabs,
                                             const float* __restrict__ att,
                                             const float* __restrict__ bias,
                                             __half* __restrict__ hout) {
  int wid = (blockIdx.x * 256 + threadIdx.x) >> 6;
  int nw = (gridDim.x * 256) >> 6;
  int lane = threadIdx.x & 63;
  int q4 = lane >> 4;            // quarter (node within wave)
  int c = (lane & 15) * 8;       // 8 channels per lane
  const __half* T12 = tabs;      // 256 x 128 fp16
  uint4 vu = *(const uint4*)(tabs + 256 * 128 + c);
  h2 v4[4] = {*reinterpret_cast<h2*>(&vu.x), *reinterpret_cast<h2*>(&vu.y),
              *reinterpret_cast<h2*>(&vu.z), *reinterpret_cast<h2*>(&vu.w)};
  float4 af0 = *(const float4*)(att + c);
  float4 af1 = *(const float4*)(att + c + 4);
  h2 a4[4] = {{(_Float16)af0.x, (_Float16)af0.y}, {(_Float16)af0.z, (_Float16)af0.w},
              {(_Float16)af1.x, (_Float16)af1.y}, {(_Float16)af1.z, (_Float16)af1.w}};
  float bb[8];
  {
    float4 b0 = *(const float4*)(bias + c);
    float4 b1 = *(const float4*)(bias + c + 4);
    bb[0] = b0.x; bb[1] = b0.y; bb[2] = b0.z; bb[3] = b0.w;
    bb[4] = b1.x; bb[5] = b1.y; bb[6] = b1.z; bb[7] = b1.w;
  }
  const h2 z2 = {(_Float16)0.f, (_Float16)0.f};
  const h2 k2 = {(_Float16)0.2f, (_Float16)0.2f};
  wid = __builtin_amdgcn_readfirstlane(wid);
  for (int nb = wid * 4; nb < N_NODES; nb += nw * 4) {
    int n = nb + q4;  // N_NODES % 4 == 0 -> always valid
    int beg = indptr[n], end1 = indptr[n + 1] - 1;  // end1 = self-loop slot
    int last = (end1 > beg) ? end1 - 1 : beg;       // clamp (may be unwritten!)
    uint4 xru = *(const uint4*)(xr + (size_t)n * 128 + c);
    h2 xrv[4] = {*reinterpret_cast<h2*>(&xru.x), *reinterpret_cast<h2*>(&xru.y),
                 *reinterpret_cast<h2*>(&xru.z), *reinterpret_cast<h2*>(&xru.w)};
    float denom = 0.f;
    float acc[8] = {0.f, 0.f, 0.f, 0.f, 0.f, 0.f, 0.f, 0.f};
    h2 els[4] = {z2, z2, z2, z2};
    int my_it = (end1 - beg + 3) >> 2;
    int m1 = my_it, m2;
    m2 = __shfl_xor(m1, 16, 64); m1 = m1 > m2 ? m1 : m2;
    m2 = __shfl_xor(m1, 32, 64); m1 = m1 > m2 ? m1 : m2;
    int iters = m1;  // wave-uniform
    for (int it = 0; it < iters; it++) {
      int j = beg + it * 4;
      int4 sc4[4]; h2 xlv[4][4]; float tt[4];
      bool val[4];
      #pragma unroll
      for (int u = 0; u < 4; u++) {
        val[u] = (j + u < end1);  // uniform within quarter
        int jj = val[u] ? j + u : last;
        sc4[u] = scode[jj];
      }
      #pragma unroll
      for (int u = 0; u < 4; u++) {
        int s = val[u] ? sc4[u].x : n;  // NEVER use poison as an address
        uint4 lv = *(const uint4*)(xl + (size_t)s * 128 + c);
        xlv[u][0] = *reinterpret_cast<h2*>(&lv.x);
        xlv[u][1] = *reinterpret_cast<h2*>(&lv.y);
        xlv[u][2] = *reinterpret_cast<h2*>(&lv.z);
        xlv[u][3] = *reinterpret_cast<h2*>(&lv.w);
      }
      #pragma unroll
      for (int u = 0; u < 4; u++) {
        int meta = val[u] ? (sc4[u].y & 255) : 255;  // row 255 = zeros
        float ec = val[u] ? __int_as_float(sc4[u].z) : 0.f;
        uint4 tv = *(const uint4*)(T12 + (size_t)meta * 128 + c);
        h2 t4[4] = {*reinterpret_cast<h2*>(&tv.x), *reinterpret_cast<h2*>(&tv.y),
                    *reinterpret_cast<h2*>(&tv.z), *reinterpret_cast<h2*>(&tv.w)};
        _Float16 eh = (_Float16)ec;
        h2 eh2 = {eh, eh};
        h2 d = z2;
        #pragma unroll
        for (int k = 0; k < 4; k++) {
          h2 el = eh2 * v4[k] + t4[k];
          h2 m = xlv[u][k] + xrv[k] + el;
          h2 l = __builtin_elementwise_max(m, z2) + k2 * __builtin_elementwise_min(m, z2);
          d += l * a4[k];
          els[k] += el;  // el=0 for invalid slots — no mask
        }
        tt[u] = (float)d[0] + (float)d[1];
      }
      // 4 independent quarter-wave reduction chains, 4 steps
      #pragma unroll
      for (int off = 1; off < 16; off <<= 1) {
        tt[0] += __shfl_xor(tt[0], off, 64);
        tt[1] += __shfl_xor(tt[1], off, 64);
        tt[2] += __shfl_xor(tt[2], off, 64);
        tt[3] += __shfl_xor(tt[3], off, 64);
      }
      #pragma unroll
      for (int u = 0; u < 4; u++) {
        float ex = val[u] ? __expf(tt[u]) : 0.f;
        denom += ex;
        #pragma unroll
        for (int k = 0; k < 4; k++) {
          acc[2 * k]     += ex * (float)xlv[u][k][0];
          acc[2 * k + 1] += ex * (float)xlv[u][k][1];
        }
      }
    }
    // self-loop (always present, processed last) — fp32 path
    int cntn = end1 - beg;
    float inv_cnt = 1.0f / (float)(cntn > 0 ? cntn : 1);
    uint4 xnu = *(const uint4*)(xl + (size_t)n * 128 + c);
    h2 xn[4] = {*reinterpret_cast<h2*>(&xnu.x), *reinterpret_cast<h2*>(&xnu.y),
                *reinterpret_cast<h2*>(&xnu.z), *reinterpret_cast<h2*>(&xnu.w)};
    float afv[8] = {af0.x, af0.y, af0.z, af0.w, af1.x, af1.y, af1.z, af1.w};
    float ts = 0.f;
    float xnf[8];
    #pragma unroll
    for (int k = 0; k < 4; k++) {
      #pragma unroll
      for (int hh = 0; hh < 2; hh++) {
        int i = 2 * k + hh;
        xnf[i] = (float)xn[k][hh];
        float m = xnf[i] + (float)xrv[k][hh] + (float)els[k][hh] * inv_cnt;
        float l = m > 0.f ? m : 0.2f * m;
        ts += l * afv[i];
      }
    }
    #pragma unroll
    for (int off = 1; off < 16; off <<= 1) ts += __shfl_xor(ts, off, 64);
    float ex = __expf(ts);
    denom += ex;
    #pragma unroll
    for (int i = 0; i < 8; i++) acc[i] += ex * xnf[i];
    float invd = 1.0f / denom;
    h2 p[4];
    #pragma unroll
    for (int k = 0; k < 4; k++) {
      float o0 = acc[2 * k] * invd + bb[2 * k];
      float o1 = acc[2 * k + 1] * invd + bb[2 * k + 1];
      o0 = o0 > 0.f ? o0 : 0.f;
      o1 = o1 > 0.f ? o1 : 0.f;
      p[k] = (h2){(_Float16)o0, (_Float16)o1};
    }
    uint4 st = make_uint4(*reinterpret_cast<unsigned*>(&p[0]),
                          *reinterpret_cast<unsigned*>(&p[1]),
                          *reinterpret_cast<unsigned*>(&p[2]),
                          *reinterpret_cast<unsigned*>(&p[3]));
    *(uint4*)(hout + (size_t)n * 128 + c) = st;
  }
}

// ---------------- readout: global max pool over 20 contiguous nodes --------
__global__ void k_readout(const __half* __restrict__ h, float* __restrict__ out) {
  int wid = (blockIdx.x * blockDim.x + threadIdx.x) >> 6;
  int lane = threadIdx.x & 63;
  if (wid >= N_GRAPHS) return;
  int c = lane * 2;
  float m0 = -1e30f, m1 = -1e30f;
  for (int i = 0; i < NPG; i++) {
    unsigned v = *(const unsigned*)(h + ((size_t)(wid * NPG + i)) * 128 + c);
    h2 f = *reinterpret_cast<h2*>(&v);
    m0 = fmaxf(m0, (float)f[0]);
    m1 = fmaxf(m1, (float)f[1]);
  }
  float2 o; o.x = m0; o.y = m1;
  *(float2*)(out + (size_t)wid * 128 + c) = o;
}

extern "C" void kernel_launch(void* const* d_in, const int* in_sizes, int n_in,
                              void* d_out, int out_size, void* d_ws, size_t ws_size,
                              hipStream_t stream) {
  (void)in_sizes; (void)n_in; (void)out_size; (void)ws_size;
  const float* x        = (const float*)d_in[0];
  const int*   eindex   = (const int*)d_in[1];
  const float* eattr    = (const float*)d_in[2];
  const float* atom_emb = (const float*)d_in[4];
  const float* bond_emb = (const float*)d_in[5];
  const float* bool_emb = (const float*)d_in[6];
  const float* Wn   = (const float*)d_in[7];
  const float* bn   = (const float*)d_in[8];
  const float* We   = (const float*)d_in[9];
  const float* be   = (const float*)d_in[10];
  const float* Wl1  = (const float*)d_in[11];
  const float* bl1  = (const float*)d_in[12];
  const float* Wr1  = (const float*)d_in[13];
  const float* br1  = (const float*)d_in[14];
  const float* Wedge1 = (const float*)d_in[15];
  const float* att1 = (const float*)d_in[16];
  const float* bias1 = (const float*)d_in[17];
  const float* Wl2  = (const float*)d_in[18];
  const float* bl2  = (const float*)d_in[19];
  const float* Wr2  = (const float*)d_in[20];
  const float* br2  = (const float*)d_in[21];
  const float* Wedge2 = (const float*)d_in[22];
  const float* att2 = (const float*)d_in[23];
  const float* bias2 = (const float*)d_in[24];

  const int* srcA = eindex;
  const int* dstA = eindex + N_EDGES;

  char* p = (char*)d_ws;
  auto alloc = [&](size_t bytes) {
    char* r = p;
    p += (bytes + 255) & ~(size_t)255;
    return r;
  };
  __half* h0     = (__half*)alloc((size_t)N_NODES * 64 * 2);
  __half* h      = (__half*)alloc((size_t)N_NODES * 128 * 2);
  __half* xl     = (__half*)alloc((size_t)N_NODES * 128 * 2);
  __half* xrb    = (__half*)alloc((size_t)N_NODES * 128 * 2);
  int*    cnt    = (int*)alloc((size_t)N_NODES * 4);
  int*    indptr = (int*)alloc((size_t)(N_NODES + 1) * 4);
  int*    cursor = (int*)alloc((size_t)N_NODES * 4);
  int4*   scode  = (int4*)alloc((size_t)(N_EDGES + N_NODES) * 16);
  __half* tabs   = (__half*)alloc((size_t)2 * TAB_STRIDE * 2);
  unsigned short* wfrag = (unsigned short*)alloc((size_t)(2 * F1 + 2 * F2) * 2);
  int*    bsum   = (int*)alloc((size_t)SCAN_NB * 4);

  (void)hipMemsetAsync(cnt, 0, (size_t)N_NODES * 4, stream);

  // fused prologue: encode | hist | tabs | prep
  k_prologue<<<NB_ENC + NB_HIST + 1 + 24, 256, 0, stream>>>(
      x, atom_emb, bool_emb, Wn, bn, h0, dstA, cnt,
      Wedge1, Wedge2, bond_emb, We, be, tabs,
      Wl1, Wr1, Wl2, Wr2, wfrag);
  k_scan1<<<SCAN_NB, 256, 0, stream>>>(cnt, bsum);
  k_scan2<<<1, 256, 0, stream>>>(bsum);
  k_scan3<<<SCAN_NB, 256, 0, stream>>>(cnt, bsum, indptr, cursor);
  k_fill<<<(N_EDGES + 255) / 256, 256, 0, stream>>>(srcA, dstA, eattr, cursor, scode);

  const unsigned short* f_l1 = wfrag;
  const unsigned short* f_r1 = wfrag + F1;
  const unsigned short* f_l2 = wfrag + 2 * F1;
  const unsigned short* f_r2 = wfrag + 2 * F1 + F2;

  const int GB2 = (N_NODES / 16 + 3) / 4;  // 1563 blocks of 4 waves

  // layer 1 (K=52 zero-padded to 64)
  k_gemm2m<64><<<GB2, 256, 0, stream>>>(h0, f_l1, f_r1, bl1, br1, xl, xrb);
  k_gat<<<2048, 256, 0, stream>>>(xl, xrb, indptr, scode, tabs, att1, bias1, h);

  // layer 2 (K=128)
  k_gemm2m<128><<<GB2, 256, 0, stream>>>(h, f_l2, f_r2, bl2, br2, xl, xrb);
  k_gat<<<2048, 256, 0, stream>>>(xl, xrb, indptr, scode, tabs + TAB_STRIDE, att2, bias2, h);

  // layer 3 (shared weights with layer 2)
  k_gemm2m<128><<<GB2, 256, 0, stream>>>(h, f_l2, f_r2, bl2, br2, xl, xrb);
  k_gat<<<2048, 256, 0, stream>>>(xl, xrb, indptr, scode, tabs + TAB_STRIDE, att2, bias2, h);

  k_readout<<<(N_GRAPHS * 64 + 255) / 256, 256, 0, stream>>>(h, (float*)d_out);
}

// Round 20
// 348.245 us; speedup vs baseline: 1.0353x; 1.0260x over previous
//
#include <hip/hip_runtime.h>
#include <hip/hip_fp16.h>

#define N_NODES 100000
#define N_EDGES 400000
#define N_GRAPHS 5000
#define NPG 20
#define SCAN_NB 256
#define SCAN_CHUNK ((N_NODES + SCAN_NB - 1) / SCAN_NB)  // 391
#define TAB_STRIDE (256 * 128 + 128)  // halves: T12[256][128] + v[128]
#define F1 8192   // ushorts per K=64 frag array (1024 frags * 8, fp16)
#define F2 16384  // ushorts per K=128 frag array (2048 frags * 8, fp16)
#define NB_ENC ((N_NODES + 255) / 256)   // 391
#define NB_HIST ((N_EDGES + 255) / 256)  // 1563

typedef __attribute__((ext_vector_type(8))) _Float16 f16x8;
typedef __attribute__((ext_vector_type(2))) _Float16 h2;
typedef __attribute__((ext_vector_type(4))) float f32x4;

// ---------------- fused prologue: encode_nodes | hist | tabs | prep ---------
__global__ __launch_bounds__(256) void k_prologue(
    const float* __restrict__ x, const float* __restrict__ atom_emb,
    const float* __restrict__ bool_emb, const float* __restrict__ Wn,
    const float* __restrict__ bn, __half* __restrict__ h0,
    const int* __restrict__ dst, int* __restrict__ cnt,
    const float* __restrict__ Wedge1, const float* __restrict__ Wedge2,
    const float* __restrict__ bond_emb, const float* __restrict__ We,
    const float* __restrict__ be, __half* __restrict__ tabs,
    const float* __restrict__ Wl1, const float* __restrict__ Wr1,
    const float* __restrict__ Wl2, const float* __restrict__ Wr2,
    unsigned short* __restrict__ fr) {
  int b = blockIdx.x, tid = threadIdx.x;
  if (b < NB_ENC) {
    // ---- node encoder: h0[N,64] fp16 (cols 52..63 zero) ----
    int n = b * 256 + tid;
    if (n >= N_NODES) return;
    const float* xr = x + (size_t)n * 14;
    __half* h = h0 + (size_t)n * 64;
    int ai = (int)xr[0];
    #pragma unroll
    for (int j = 0; j < 16; j++) h[j] = __float2half(atom_emb[ai * 16 + j]);
    float xc[10];
    #pragma unroll
    for (int k = 0; k < 10; k++) xc[k] = xr[1 + k];
    #pragma unroll
    for (int c = 0; c < 30; c++) {
      float s = bn[c];
      #pragma unroll
      for (int k = 0; k < 10; k++) s += xc[k] * Wn[k * 30 + c];
      h[16 + c] = __float2half(s);
    }
    #pragma unroll
    for (int t = 0; t < 3; t++) {
      int bb = (int)xr[11 + t];
      h[46 + 2 * t]     = __float2half(bool_emb[2 * bb]);
      h[46 + 2 * t + 1] = __float2half(bool_emb[2 * bb + 1]);
    }
    #pragma unroll
    for (int j = 52; j < 64; j++) h[j] = __float2half(0.0f);
  } else if (b < NB_ENC + NB_HIST) {
    // ---- in-degree histogram ----
    int e = (b - NB_ENC) * 256 + tid;
    if (e >= N_EDGES) return;
    atomicAdd(cnt + dst[e], 1);
  } else if (b == NB_ENC + NB_HIST) {
    // ---- fused logit table (fp16): T12[combo*32+bi], v; rows 22..31 = 0 ----
    int s = tid >> 7, c = tid & 127;
    const float* W = s ? Wedge2 : Wedge1;
    __half* T12 = tabs + (size_t)s * TAB_STRIDE;
    __half* v   = T12 + 256 * 128;
    float w8 = W[8 * 128 + c], w9 = W[9 * 128 + c];
    v[c] = __float2half(We[0] * w8 + We[1] * w9);
    float cst = be[0] * w8 + be[1] * w9;
    float bond[22];
    for (int bb = 0; bb < 22; bb++) {
      float acc = 0.f;
      #pragma unroll
      for (int k = 0; k < 8; k++) acc += bond_emb[bb * 8 + k] * W[k * 128 + c];
      bond[bb] = acc;
    }
    for (int combo = 0; combo < 8; combo++) {
      float t2 = cst;
      #pragma unroll
      for (int tt = 0; tt < 3; tt++) {
        int bt = (combo >> tt) & 1;
        t2 += bool_emb[bt * 2 + 0] * W[(10 + 2 * tt + 0) * 128 + c];
        t2 += bool_emb[bt * 2 + 1] * W[(10 + 2 * tt + 1) * 128 + c];
      }
      for (int bb = 0; bb < 22; bb++)
        T12[(combo * 32 + bb) * 128 + c] = __float2half(bond[bb] + t2);
      for (int bb = 22; bb < 32; bb++)   // incl. row 255 = zero (invalid slots)
        T12[(combo * 32 + bb) * 128 + c] = __float2half(0.f);
    }
  } else {
    // ---- W -> MFMA B-fragment prep (fp16, 8 halves = 16 B per frag) ----
    int g = (b - (NB_ENC + NB_HIST + 1)) * 256 + tid;
    const float* W; int K; unsigned short* base; int fl;
    if (g < 1024)      { W = Wl1; K = 52;  base = fr;               fl = g; }
    else if (g < 2048) { W = Wr1; K = 52;  base = fr + F1;          fl = g - 1024; }
    else if (g < 4096) { W = Wl2; K = 128; base = fr + 2 * F1;      fl = g - 2048; }
    else if (g < 6144) { W = Wr2; K = 128; base = fr + 2 * F1 + F2; fl = g - 4096; }
    else return;
    int l = fl & 63, ctn = fl >> 6;
    int tn = ctn & 7, c = ctn >> 3;
    int n = tn * 16 + (l & 15);
    int kb = c * 32 + (l >> 4) * 8;
    unsigned h8[8];
    #pragma unroll
    for (int j = 0; j < 8; j++) {
      int k = kb + j;
      float v = (k < K) ? W[(size_t)k * 128 + n] : 0.f;
      __half hv = __float2half(v);
      h8[j] = (unsigned)*(unsigned short*)&hv;
    }
    uint4 hv4 = make_uint4(h8[0] | (h8[1] << 16), h8[2] | (h8[3] << 16),
                           h8[4] | (h8[5] << 16), h8[6] | (h8[7] << 16));
    *(uint4*)(base + (size_t)fl * 8) = hv4;
  }
}

// ---------------- scan phase 1: per-chunk sums ------------------------------
__global__ __launch_bounds__(256) void k_scan1(const int* __restrict__ cnt,
                                               int* __restrict__ bsum) {
  __shared__ int red[256];
  int b = blockIdx.x, t = threadIdx.x;
  int beg = b * SCAN_CHUNK;
  int end = beg + SCAN_CHUNK; if (end > N_NODES) end = N_NODES;
  int s = 0;
  for (int i = beg + t; i < end; i += 256) s += cnt[i] + 1;
  red[t] = s;
  __syncthreads();
  for (int off = 128; off > 0; off >>= 1) {
    if (t < off) red[t] += red[t + off];
    __syncthreads();
  }
  if (t == 0) bsum[b] = red[0];
}

// ---------------- scan phase 2+3 fused: each block re-scans bsum ------------
// (saves the separate 1-block k_scan2 launch; 256 redundant 256-int scans
//  are ~free vs a dispatch boundary)
__global__ __launch_bounds__(256) void k_scan3(const int* __restrict__ cnt,
                                               const int* __restrict__ bsum,
                                               int* __restrict__ indptr,
                                               int* __restrict__ cursor) {
  __shared__ int sh[256];
  __shared__ int carry;
  int b = blockIdx.x, t = threadIdx.x;
  // inline exclusive scan of bsum (raw block sums) -> this block's base
  sh[t] = bsum[t];
  __syncthreads();
  for (int off = 1; off < 256; off <<= 1) {
    int v = (t >= off) ? sh[t - off] : 0;
    __syncthreads();
    sh[t] += v;
    __syncthreads();
  }
  if (t == 0) carry = (b > 0) ? sh[b - 1] : 0;
  __syncthreads();
  int beg = b * SCAN_CHUNK;
  int end = beg + SCAN_CHUNK; if (end > N_NODES) end = N_NODES;
  for (int base = beg; base < end; base += 256) {
    int i = base + t;
    int v = (i < end) ? cnt[i] + 1 : 0;
    sh[t] = v;
    __syncthreads();
    for (int off = 1; off < 256; off <<= 1) {
      int u = (t >= off) ? sh[t - off] : 0;
      __syncthreads();
      sh[t] += u;
      __syncthreads();
    }
    int excl = sh[t] - v;
    if (i < end) {
      int val = carry + excl;
      indptr[i] = val;
      cursor[i] = val;
    }
    __syncthreads();
    if (t == 255) carry += sh[255];
    __syncthreads();
  }
  if (b == 0 && t == 0) indptr[N_NODES] = N_EDGES + N_NODES;
}

// ---------------- CSR fill: ordinary edges into slots [beg, end-1) ----------
__global__ void k_fill(const int* __restrict__ srcA,
                       const int* __restrict__ dst,
                       const float* __restrict__ eattr,
                       int* __restrict__ cursor,
                       int4* __restrict__ scode) {
  int e = blockIdx.x * blockDim.x + threadIdx.x;
  if (e >= N_EDGES) return;
  const float* r = eattr + (size_t)e * 5;
  int bi = (int)r[0];
  float ec = r[1];
  int combo = (int)r[2] + 2 * (int)r[3] + 4 * (int)r[4];
  int meta = bi | (combo << 5);
  int d = dst[e];
  int p = atomicAdd(&cursor[d], 1);
  scode[p] = make_int4(srcA[e], meta, __float_as_int(ec), 0);
}

// ---------------- MFMA dual GEMM, M=16/wave, 64k-chunk LDS, LDS epilogue ----
template <int KPAD>
__global__ __launch_bounds__(256, 4) void k_gemm2m(const __half* __restrict__ A,
                                                   const unsigned short* __restrict__ WfL,
                                                   const unsigned short* __restrict__ WfR,
                                                   const float* __restrict__ bl_,
                                                   const float* __restrict__ br_,
                                                   __half* __restrict__ outl,
                                                   __half* __restrict__ outr) {
  __shared__ unsigned short Bs[2][8192];  // L, R (16 KB each, 64 k's)
  const int tid = threadIdx.x;
  const int wv = tid >> 6, lane = tid & 63;
  const int tw = blockIdx.x * 4 + wv;
  const bool active = (tw < N_NODES / 16);  // tail waves stay for barriers
  const int ml = lane & 15, q = lane >> 4;
  const int m0 = active ? tw * 16 : 0;
  f32x4 accL[8], accR[8];
  #pragma unroll
  for (int t = 0; t < 8; t++) {
    accL[t] = (f32x4){0.f, 0.f, 0.f, 0.f};
    accR[t] = (f32x4){0.f, 0.f, 0.f, 0.f};
  }
  const _Float16* ar0 = (const _Float16*)A + (size_t)(m0 + ml) * KPAD + q * 8;
  constexpr int NC2 = KPAD / 64;
  for (int c2 = 0; c2 < NC2; c2++) {
    // stage 64-k chunk: 1024 frags (16 B each) per W = 16 KB per W
    #pragma unroll
    for (int i0 = 0; i0 < 1024; i0 += 256) {
      int i = i0 + tid;
      size_t g = ((size_t)c2 * 1024 + i) * 8;
      *(uint4*)(&Bs[0][i * 8]) = *(const uint4*)(WfL + g);
      *(uint4*)(&Bs[1][i * 8]) = *(const uint4*)(WfR + g);
    }
    __syncthreads();
    #pragma unroll
    for (int sub = 0; sub < 2; sub++) {
      f16x8 a = *(const f16x8*)(ar0 + c2 * 64 + sub * 32);
      #pragma unroll
      for (int t = 0; t < 8; t++) {
        int idx = (sub * 512 + t * 64 + lane) * 8;
        f16x8 bL = *(const f16x8*)(&Bs[0][idx]);
        f16x8 bR = *(const f16x8*)(&Bs[1][idx]);
        accL[t] = __builtin_amdgcn_mfma_f32_16x16x32_f16(a, bL, accL[t], 0, 0, 0);
        accR[t] = __builtin_amdgcn_mfma_f32_16x16x32_f16(a, bR, accR[t], 0, 0, 0);
      }
    }
    __syncthreads();
  }
  // one barrier so all waves finish reading Bs before we reuse it as scratch
  __syncthreads();
  if (!active) return;
  // epilogue: acc (C/D layout col=lane&15, row=quad*4+reg) -> per-wave 4 KB
  // LDS transpose -> coalesced 16 B/lane stores.
  __half* eb = (__half*)&Bs[0][0] + wv * 2048;  // 16 rows x 128 cols fp16
  const int srow = q * 4;           // rows this lane writes
  const int rrow0 = lane >> 4;      // read-back: row p*4 + lane/16
  const int rcol = (lane & 15) * 8; // read-back col
  // ---- L ----
  #pragma unroll
  for (int t = 0; t < 8; t++) {
    int n = t * 16 + ml;
    float bL = bl_[n];
    #pragma unroll
    for (int r = 0; r < 4; r++)
      eb[(srow + r) * 128 + n] = __float2half(accL[t][r] + bL);
  }
  #pragma unroll
  for (int pp = 0; pp < 4; pp++) {
    uint4 v = *(const uint4*)(eb + pp * 512 + lane * 8);
    *(uint4*)(outl + (size_t)(m0 + pp * 4 + rrow0) * 128 + rcol) = v;
  }
  // ---- R (reuse same region; within-wave LDS ordering is tracked) ----
  #pragma unroll
  for (int t = 0; t < 8; t++) {
    int n = t * 16 + ml;
    float bR = br_[n];
    #pragma unroll
    for (int r = 0; r < 4; r++)
      eb[(srow + r) * 128 + n] = __float2half(accR[t][r] + bR);
  }
  #pragma unroll
  for (int pp = 0; pp < 4; pp++) {
    uint4 v = *(const uint4*)(eb + pp * 512 + lane * 8);
    *(uint4*)(outr + (size_t)(m0 + pp * 4 + rrow0) * 128 + rcol) = v;
  }
}

// ---------------- GATv2 edge pass: 16 lanes/node (4 nodes/wave) -------------
// 8 ch/lane => 16 B/lane gathers (dwordx4, 4 rows per instruction);
// 4-step quarter-wave reductions. T12 row 255 = 0 so invalid lock-step slots
// contribute el=0 with no masking. Plain-sum softmax (logits O(0.3)).
// Never use unvalidated scode data as an address.
// Grid: 2048 persistent blocks (grid-stride loop smooths degree imbalance —
// one-pass-per-wave grids measured WORSE: r18 52 vs 48 us).
__global__ __launch_bounds__(256) void k_gat(const __half* __restrict__ xl,
                                             const __half* __restrict__ xr,
                                             const int* __restrict__ indptr,
                                             const int4* __restrict__ scode,
                                             const __half* __restrict__ tabs,
                                             const float* __restrict__ att,
                                             const float* __restrict__ bias,
                                             __half* __restrict__ hout) {
  int wid = (blockIdx.x * 256 + threadIdx.x) >> 6;
  int nw = (gridDim.x * 256) >> 6;
  int lane = threadIdx.x & 63;
  int q4 = lane >> 4;            // quarter (node within wave)
  int c = (lane & 15) * 8;       // 8 channels per lane
  const __half* T12 = tabs;      // 256 x 128 fp16
  uint4 vu = *(const uint4*)(tabs + 256 * 128 + c);
  h2 v4[4] = {*reinterpret_cast<h2*>(&vu.x), *reinterpret_cast<h2*>(&vu.y),
              *reinterpret_cast<h2*>(&vu.z), *reinterpret_cast<h2*>(&vu.w)};
  float4 af0 = *(const float4*)(att + c);
  float4 af1 = *(const float4*)(att + c + 4);
  h2 a4[4] = {{(_Float16)af0.x, (_Float16)af0.y}, {(_Float16)af0.z, (_Float16)af0.w},
              {(_Float16)af1.x, (_Float16)af1.y}, {(_Float16)af1.z, (_Float16)af1.w}};
  float bb[8];
  {
    float4 b0 = *(const float4*)(bias + c);
    float4 b1 = *(const float4*)(bias + c + 4);
    bb[0] = b0.x; bb[1] = b0.y; bb[2] = b0.z; bb[3] = b0.w;
    bb[4] = b1.x; bb[5] = b1.y; bb[6] = b1.z; bb[7] = b1.w;
  }
  const h2 z2 = {(_Float16)0.f, (_Float16)0.f};
  const h2 k2 = {(_Float16)0.2f, (_Float16)0.2f};
  wid = __builtin_amdgcn_readfirstlane(wid);
  for (int nb = wid * 4; nb < N_NODES; nb += nw * 4) {
    int n = nb + q4;  // N_NODES % 4 == 0 -> always valid
    int beg = indptr[n], end1 = indptr[n + 1] - 1;  // end1 = self-loop slot
    int last = (end1 > beg) ? end1 - 1 : beg;       // clamp (may be unwritten!)
    uint4 xru = *(const uint4*)(xr + (size_t)n * 128 + c);
    h2 xrv[4] = {*reinterpret_cast<h2*>(&xru.x), *reinterpret_cast<h2*>(&xru.y),
                 *reinterpret_cast<h2*>(&xru.z), *reinterpret_cast<h2*>(&xru.w)};
    float denom = 0.f;
    float acc[8] = {0.f, 0.f, 0.f, 0.f, 0.f, 0.f, 0.f, 0.f};
    h2 els[4] = {z2, z2, z2, z2};
    int my_it = (end1 - beg + 3) >> 2;
    int m1 = my_it, m2;
    m2 = __shfl_xor(m1, 16, 64); m1 = m1 > m2 ? m1 : m2;
    m2 = __shfl_xor(m1, 32, 64); m1 = m1 > m2 ? m1 : m2;
    int iters = m1;  // wave-uniform
    for (int it = 0; it < iters; it++) {
      int j = beg + it * 4;
      int4 sc4[4]; h2 xlv[4][4]; float tt[4];
      bool val[4];
      #pragma unroll
      for (int u = 0; u < 4; u++) {
        val[u] = (j + u < end1);  // uniform within quarter
        int jj = val[u] ? j + u : last;
        sc4[u] = scode[jj];
      }
      #pragma unroll
      for (int u = 0; u < 4; u++) {
        int s = val[u] ? sc4[u].x : n;  // NEVER use poison as an address
        uint4 lv = *(const uint4*)(xl + (size_t)s * 128 + c);
        xlv[u][0] = *reinterpret_cast<h2*>(&lv.x);
        xlv[u][1] = *reinterpret_cast<h2*>(&lv.y);
        xlv[u][2] = *reinterpret_cast<h2*>(&lv.z);
        xlv[u][3] = *reinterpret_cast<h2*>(&lv.w);
      }
      #pragma unroll
      for (int u = 0; u < 4; u++) {
        int meta = val[u] ? (sc4[u].y & 255) : 255;  // row 255 = zeros
        float ec = val[u] ? __int_as_float(sc4[u].z) : 0.f;
        uint4 tv = *(const uint4*)(T12 + (size_t)meta * 128 + c);
        h2 t4[4] = {*reinterpret_cast<h2*>(&tv.x), *reinterpret_cast<h2*>(&tv.y),
                    *reinterpret_cast<h2*>(&tv.z), *reinterpret_cast<h2*>(&tv.w)};
        _Float16 eh = (_Float16)ec;
        h2 eh2 = {eh, eh};
        h2 d = z2;
        #pragma unroll
        for (int k = 0; k < 4; k++) {
          h2 el = eh2 * v4[k] + t4[k];
          h2 m = xlv[u][k] + xrv[k] + el;
          h2 l = __builtin_elementwise_max(m, z2) + k2 * __builtin_elementwise_min(m, z2);
          d += l * a4[k];
          els[k] += el;  // el=0 for invalid slots — no mask
        }
        tt[u] = (float)d[0] + (float)d[1];
      }
      // 4 independent quarter-wave reduction chains, 4 steps
      #pragma unroll
      for (int off = 1; off < 16; off <<= 1) {
        tt[0] += __shfl_xor(tt[0], off, 64);
        tt[1] += __shfl_xor(tt[1], off, 64);
        tt[2] += __shfl_xor(tt[2], off, 64);
        tt[3] += __shfl_xor(tt[3], off, 64);
      }
      #pragma unroll
      for (int u = 0; u < 4; u++) {
        float ex = val[u] ? __expf(tt[u]) : 0.f;
        denom += ex;
        #pragma unroll
        for (int k = 0; k < 4; k++) {
          acc[2 * k]     += ex * (float)xlv[u][k][0];
          acc[2 * k + 1] += ex * (float)xlv[u][k][1];
        }
      }
    }
    // self-loop (always present, processed last) — fp32 path
    int cntn = end1 - beg;
    float inv_cnt = 1.0f / (float)(cntn > 0 ? cntn : 1);
    uint4 xnu = *(const uint4*)(xl + (size_t)n * 128 + c);
    h2 xn[4] = {*reinterpret_cast<h2*>(&xnu.x), *reinterpret_cast<h2*>(&xnu.y),
                *reinterpret_cast<h2*>(&xnu.z), *reinterpret_cast<h2*>(&xnu.w)};
    float afv[8] = {af0.x, af0.y, af0.z, af0.w, af1.x, af1.y, af1.z, af1.w};
    float ts = 0.f;
    float xnf[8];
    #pragma unroll
    for (int k = 0; k < 4; k++) {
      #pragma unroll
      for (int hh = 0; hh < 2; hh++) {
        int i = 2 * k + hh;
        xnf[i] = (float)xn[k][hh];
        float m = xnf[i] + (float)xrv[k][hh] + (float)els[k][hh] * inv_cnt;
        float l = m > 0.f ? m : 0.2f * m;
        ts += l * afv[i];
      }
    }
    #pragma unroll
    for (int off = 1; off < 16; off <<= 1) ts += __shfl_xor(ts, off, 64);
    float ex = __expf(ts);
    denom += ex;
    #pragma unroll
    for (int i = 0; i < 8; i++) acc[i] += ex * xnf[i];
    float invd = 1.0f / denom;
    h2 p[4];
    #pragma unroll
    for (int k = 0; k < 4; k++) {
      float o0 = acc[2 * k] * invd + bb[2 * k];
      float o1 = acc[2 * k + 1] * invd + bb[2 * k + 1];
      o0 = o0 > 0.f ? o0 : 0.f;
      o1 = o1 > 0.f ? o1 : 0.f;
      p[k] = (h2){(_Float16)o0, (_Float16)o1};
    }
    uint4 st = make_uint4(*reinterpret_cast<unsigned*>(&p[0]),
                          *reinterpret_cast<unsigned*>(&p[1]),
                          *reinterpret_cast<unsigned*>(&p[2]),
                          *reinterpret_cast<unsigned*>(&p[3]));
    *(uint4*)(hout + (size_t)n * 128 + c) = st;
  }
}

// ---------------- readout: global max pool over 20 contiguous nodes --------
__global__ void k_readout(const __half* __restrict__ h, float* __restrict__ out) {
  int wid = (blockIdx.x * blockDim.x + threadIdx.x) >> 6;
  int lane = threadIdx.x & 63;
  if (wid >= N_GRAPHS) return;
  int c = lane * 2;
  float m0 = -1e30f, m1 = -1e30f;
  for (int i = 0; i < NPG; i++) {
    unsigned v = *(const unsigned*)(h + ((size_t)(wid * NPG + i)) * 128 + c);
    h2 f = *reinterpret_cast<h2*>(&v);
    m0 = fmaxf(m0, (float)f[0]);
    m1 = fmaxf(m1, (float)f[1]);
  }
  float2 o; o.x = m0; o.y = m1;
  *(float2*)(out + (size_t)wid * 128 + c) = o;
}

extern "C" void kernel_launch(void* const* d_in, const int* in_sizes, int n_in,
                              void* d_out, int out_size, void* d_ws, size_t ws_size,
                              hipStream_t stream) {
  (void)in_sizes; (void)n_in; (void)out_size; (void)ws_size;
  const float* x        = (const float*)d_in[0];
  const int*   eindex   = (const int*)d_in[1];
  const float* eattr    = (const float*)d_in[2];
  const float* atom_emb = (const float*)d_in[4];
  const float* bond_emb = (const float*)d_in[5];
  const float* bool_emb = (const float*)d_in[6];
  const float* Wn   = (const float*)d_in[7];
  const float* bn   = (const float*)d_in[8];
  const float* We   = (const float*)d_in[9];
  const float* be   = (const float*)d_in[10];
  const float* Wl1  = (const float*)d_in[11];
  const float* bl1  = (const float*)d_in[12];
  const float* Wr1  = (const float*)d_in[13];
  const float* br1  = (const float*)d_in[14];
  const float* Wedge1 = (const float*)d_in[15];
  const float* att1 = (const float*)d_in[16];
  const float* bias1 = (const float*)d_in[17];
  const float* Wl2  = (const float*)d_in[18];
  const float* bl2  = (const float*)d_in[19];
  const float* Wr2  = (const float*)d_in[20];
  const float* br2  = (const float*)d_in[21];
  const float* Wedge2 = (const float*)d_in[22];
  const float* att2 = (const float*)d_in[23];
  const float* bias2 = (const float*)d_in[24];

  const int* srcA = eindex;
  const int* dstA = eindex + N_EDGES;

  char* p = (char*)d_ws;
  auto alloc = [&](size_t bytes) {
    char* r = p;
    p += (bytes + 255) & ~(size_t)255;
    return r;
  };
  __half* h0     = (__half*)alloc((size_t)N_NODES * 64 * 2);
  __half* h      = (__half*)alloc((size_t)N_NODES * 128 * 2);
  __half* xl     = (__half*)alloc((size_t)N_NODES * 128 * 2);
  __half* xrb    = (__half*)alloc((size_t)N_NODES * 128 * 2);
  int*    cnt    = (int*)alloc((size_t)N_NODES * 4);
  int*    indptr = (int*)alloc((size_t)(N_NODES + 1) * 4);
  int*    cursor = (int*)alloc((size_t)N_NODES * 4);
  int4*   scode  = (int4*)alloc((size_t)(N_EDGES + N_NODES) * 16);
  __half* tabs   = (__half*)alloc((size_t)2 * TAB_STRIDE * 2);
  unsigned short* wfrag = (unsigned short*)alloc((size_t)(2 * F1 + 2 * F2) * 2);
  int*    bsum   = (int*)alloc((size_t)SCAN_NB * 4);

  (void)hipMemsetAsync(cnt, 0, (size_t)N_NODES * 4, stream);

  // fused prologue: encode | hist | tabs | prep
  k_prologue<<<NB_ENC + NB_HIST + 1 + 24, 256, 0, stream>>>(
      x, atom_emb, bool_emb, Wn, bn, h0, dstA, cnt,
      Wedge1, Wedge2, bond_emb, We, be, tabs,
      Wl1, Wr1, Wl2, Wr2, wfrag);
  k_scan1<<<SCAN_NB, 256, 0, stream>>>(cnt, bsum);
  k_scan3<<<SCAN_NB, 256, 0, stream>>>(cnt, bsum, indptr, cursor);
  k_fill<<<(N_EDGES + 255) / 256, 256, 0, stream>>>(srcA, dstA, eattr, cursor, scode);

  const unsigned short* f_l1 = wfrag;
  const unsigned short* f_r1 = wfrag + F1;
  const unsigned short* f_l2 = wfrag + 2 * F1;
  const unsigned short* f_r2 = wfrag + 2 * F1 + F2;

  const int GB2 = (N_NODES / 16 + 3) / 4;  // 1563 blocks of 4 waves

  // layer 1 (K=52 zero-padded to 64)
  k_gemm2m<64><<<GB2, 256, 0, stream>>>(h0, f_l1, f_r1, bl1, br1, xl, xrb);
  k_gat<<<2048, 256, 0, stream>>>(xl, xrb, indptr, scode, tabs, att1, bias1, h);

  // layer 2 (K=128)
  k_gemm2m<128><<<GB2, 256, 0, stream>>>(h, f_l2, f_r2, bl2, br2, xl, xrb);
  k_gat<<<2048, 256, 0, stream>>>(xl, xrb, indptr, scode, tabs + TAB_STRIDE, att2, bias2, h);

  // layer 3 (shared weights with layer 2)
  k_gemm2m<128><<<GB2, 256, 0, stream>>>(h, f_l2, f_r2, bl2, br2, xl, xrb);
  k_gat<<<2048, 256, 0, stream>>>(xl, xrb, indptr, scode, tabs + TAB_STRIDE, att2, bias2, h);

  k_readout<<<(N_GRAPHS * 64 + 255) / 256, 256, 0, stream>>>(h, (float*)d_out);
}

// Round 21
// 346.288 us; speedup vs baseline: 1.0411x; 1.0057x over previous
//
#include <hip/hip_runtime.h>
#include <hip/hip_fp16.h>

#define N_NODES 100000
#define N_EDGES 400000
#define N_GRAPHS 5000
#define NPG 20
#define SCAN_NB 256
#define SCAN_CHUNK ((N_NODES + SCAN_NB - 1) / SCAN_NB)  // 391
#define TAB_STRIDE (256 * 128 + 128)  // halves: T12[256][128] + v[128]
#define F1 8192   // ushorts per K=64 frag array (1024 frags * 8, fp16)
#define F2 16384  // ushorts per K=128 frag array (2048 frags * 8, fp16)
#define NB_ENC ((N_NODES + 255) / 256)   // 391
#define NB_HIST ((N_EDGES + 255) / 256)  // 1563

typedef __attribute__((ext_vector_type(8))) _Float16 f16x8;
typedef __attribute__((ext_vector_type(2))) _Float16 h2;
typedef __attribute__((ext_vector_type(4))) float f32x4;

// ---------------- fused prologue: encode_nodes | hist | tabs | prep ---------
__global__ __launch_bounds__(256) void k_prologue(
    const float* __restrict__ x, const float* __restrict__ atom_emb,
    const float* __restrict__ bool_emb, const float* __restrict__ Wn,
    const float* __restrict__ bn, __half* __restrict__ h0,
    const int* __restrict__ dst, int* __restrict__ cnt,
    const float* __restrict__ Wedge1, const float* __restrict__ Wedge2,
    const float* __restrict__ bond_emb, const float* __restrict__ We,
    const float* __restrict__ be, __half* __restrict__ tabs,
    const float* __restrict__ Wl1, const float* __restrict__ Wr1,
    const float* __restrict__ Wl2, const float* __restrict__ Wr2,
    unsigned short* __restrict__ fr) {
  int b = blockIdx.x, tid = threadIdx.x;
  if (b < NB_ENC) {
    // ---- node encoder: h0[N,64] fp16, row built in regs, 8x dwordx4 store --
    int n = b * 256 + tid;
    if (n >= N_NODES) return;
    const float* xr = x + (size_t)n * 14;
    int ai = (int)xr[0];
    _Float16 hr[64];
    #pragma unroll
    for (int j = 0; j < 16; j++) hr[j] = (_Float16)atom_emb[ai * 16 + j];
    float xc[10];
    #pragma unroll
    for (int k = 0; k < 10; k++) xc[k] = xr[1 + k];
    #pragma unroll
    for (int c = 0; c < 30; c++) {
      float s = bn[c];
      #pragma unroll
      for (int k = 0; k < 10; k++) s += xc[k] * Wn[k * 30 + c];
      hr[16 + c] = (_Float16)s;
    }
    #pragma unroll
    for (int t = 0; t < 3; t++) {
      int bb = (int)xr[11 + t];
      hr[46 + 2 * t]     = (_Float16)bool_emb[2 * bb];
      hr[46 + 2 * t + 1] = (_Float16)bool_emb[2 * bb + 1];
    }
    #pragma unroll
    for (int j = 52; j < 64; j++) hr[j] = (_Float16)0.0f;
    uint4* d4 = (uint4*)(h0 + (size_t)n * 64);
    const uint4* s4 = (const uint4*)hr;
    #pragma unroll
    for (int j = 0; j < 8; j++) d4[j] = s4[j];
  } else if (b < NB_ENC + NB_HIST) {
    // ---- in-degree histogram ----
    int e = (b - NB_ENC) * 256 + tid;
    if (e >= N_EDGES) return;
    atomicAdd(cnt + dst[e], 1);
  } else if (b == NB_ENC + NB_HIST) {
    // ---- fused logit table (fp16): T12[combo*32+bi], v; rows 22..31 = 0 ----
    int s = tid >> 7, c = tid & 127;
    const float* W = s ? Wedge2 : Wedge1;
    __half* T12 = tabs + (size_t)s * TAB_STRIDE;
    __half* v   = T12 + 256 * 128;
    float w8 = W[8 * 128 + c], w9 = W[9 * 128 + c];
    v[c] = __float2half(We[0] * w8 + We[1] * w9);
    float cst = be[0] * w8 + be[1] * w9;
    float bond[22];
    for (int bb = 0; bb < 22; bb++) {
      float acc = 0.f;
      #pragma unroll
      for (int k = 0; k < 8; k++) acc += bond_emb[bb * 8 + k] * W[k * 128 + c];
      bond[bb] = acc;
    }
    for (int combo = 0; combo < 8; combo++) {
      float t2 = cst;
      #pragma unroll
      for (int tt = 0; tt < 3; tt++) {
        int bt = (combo >> tt) & 1;
        t2 += bool_emb[bt * 2 + 0] * W[(10 + 2 * tt + 0) * 128 + c];
        t2 += bool_emb[bt * 2 + 1] * W[(10 + 2 * tt + 1) * 128 + c];
      }
      for (int bb = 0; bb < 22; bb++)
        T12[(combo * 32 + bb) * 128 + c] = __float2half(bond[bb] + t2);
      for (int bb = 22; bb < 32; bb++)   // incl. row 255 = zero (invalid slots)
        T12[(combo * 32 + bb) * 128 + c] = __float2half(0.f);
    }
  } else {
    // ---- W -> MFMA B-fragment prep (fp16, 8 halves = 16 B per frag) ----
    int g = (b - (NB_ENC + NB_HIST + 1)) * 256 + tid;
    const float* W; int K; unsigned short* base; int fl;
    if (g < 1024)      { W = Wl1; K = 52;  base = fr;               fl = g; }
    else if (g < 2048) { W = Wr1; K = 52;  base = fr + F1;          fl = g - 1024; }
    else if (g < 4096) { W = Wl2; K = 128; base = fr + 2 * F1;      fl = g - 2048; }
    else if (g < 6144) { W = Wr2; K = 128; base = fr + 2 * F1 + F2; fl = g - 4096; }
    else return;
    int l = fl & 63, ctn = fl >> 6;
    int tn = ctn & 7, c = ctn >> 3;
    int n = tn * 16 + (l & 15);
    int kb = c * 32 + (l >> 4) * 8;
    unsigned h8[8];
    #pragma unroll
    for (int j = 0; j < 8; j++) {
      int k = kb + j;
      float v = (k < K) ? W[(size_t)k * 128 + n] : 0.f;
      __half hv = __float2half(v);
      h8[j] = (unsigned)*(unsigned short*)&hv;
    }
    uint4 hv4 = make_uint4(h8[0] | (h8[1] << 16), h8[2] | (h8[3] << 16),
                           h8[4] | (h8[5] << 16), h8[6] | (h8[7] << 16));
    *(uint4*)(base + (size_t)fl * 8) = hv4;
  }
}

// ---------------- scan phase 1: per-chunk sums ------------------------------
__global__ __launch_bounds__(256) void k_scan1(const int* __restrict__ cnt,
                                               int* __restrict__ bsum) {
  __shared__ int red[256];
  int b = blockIdx.x, t = threadIdx.x;
  int beg = b * SCAN_CHUNK;
  int end = beg + SCAN_CHUNK; if (end > N_NODES) end = N_NODES;
  int s = 0;
  for (int i = beg + t; i < end; i += 256) s += cnt[i] + 1;
  red[t] = s;
  __syncthreads();
  for (int off = 128; off > 0; off >>= 1) {
    if (t < off) red[t] += red[t + off];
    __syncthreads();
  }
  if (t == 0) bsum[b] = red[0];
}

// ---------------- scan phase 2+3 fused: each block re-scans bsum ------------
__global__ __launch_bounds__(256) void k_scan3(const int* __restrict__ cnt,
                                               const int* __restrict__ bsum,
                                               int* __restrict__ indptr,
                                               int* __restrict__ cursor) {
  __shared__ int sh[256];
  __shared__ int carry;
  int b = blockIdx.x, t = threadIdx.x;
  sh[t] = bsum[t];
  __syncthreads();
  for (int off = 1; off < 256; off <<= 1) {
    int v = (t >= off) ? sh[t - off] : 0;
    __syncthreads();
    sh[t] += v;
    __syncthreads();
  }
  if (t == 0) carry = (b > 0) ? sh[b - 1] : 0;
  __syncthreads();
  int beg = b * SCAN_CHUNK;
  int end = beg + SCAN_CHUNK; if (end > N_NODES) end = N_NODES;
  for (int base = beg; base < end; base += 256) {
    int i = base + t;
    int v = (i < end) ? cnt[i] + 1 : 0;
    sh[t] = v;
    __syncthreads();
    for (int off = 1; off < 256; off <<= 1) {
      int u = (t >= off) ? sh[t - off] : 0;
      __syncthreads();
      sh[t] += u;
      __syncthreads();
    }
    int excl = sh[t] - v;
    if (i < end) {
      int val = carry + excl;
      indptr[i] = val;
      cursor[i] = val;
    }
    __syncthreads();
    if (t == 255) carry += sh[255];
    __syncthreads();
  }
  if (b == 0 && t == 0) indptr[N_NODES] = N_EDGES + N_NODES;
}

// ---------------- CSR fill: ordinary edges into slots [beg, end-1) ----------
__global__ void k_fill(const int* __restrict__ srcA,
                       const int* __restrict__ dst,
                       const float* __restrict__ eattr,
                       int* __restrict__ cursor,
                       int4* __restrict__ scode) {
  int e = blockIdx.x * blockDim.x + threadIdx.x;
  if (e >= N_EDGES) return;
  const float* r = eattr + (size_t)e * 5;
  int bi = (int)r[0];
  float ec = r[1];
  int combo = (int)r[2] + 2 * (int)r[3] + 4 * (int)r[4];
  int meta = bi | (combo << 5);
  int d = dst[e];
  int p = atomicAdd(&cursor[d], 1);
  scode[p] = make_int4(srcA[e], meta, __float_as_int(ec), 0);
}

// ---------------- MFMA dual GEMM, M=16/wave, 64k-chunk LDS, LDS epilogue ----
template <int KPAD>
__global__ __launch_bounds__(256, 4) void k_gemm2m(const __half* __restrict__ A,
                                                   const unsigned short* __restrict__ WfL,
                                                   const unsigned short* __restrict__ WfR,
                                                   const float* __restrict__ bl_,
                                                   const float* __restrict__ br_,
                                                   __half* __restrict__ outl,
                                                   __half* __restrict__ outr) {
  __shared__ unsigned short Bs[2][8192];  // L, R (16 KB each, 64 k's)
  const int tid = threadIdx.x;
  const int wv = tid >> 6, lane = tid & 63;
  const int tw = blockIdx.x * 4 + wv;
  const bool active = (tw < N_NODES / 16);  // tail waves stay for barriers
  const int ml = lane & 15, q = lane >> 4;
  const int m0 = active ? tw * 16 : 0;
  f32x4 accL[8], accR[8];
  #pragma unroll
  for (int t = 0; t < 8; t++) {
    accL[t] = (f32x4){0.f, 0.f, 0.f, 0.f};
    accR[t] = (f32x4){0.f, 0.f, 0.f, 0.f};
  }
  const _Float16* ar0 = (const _Float16*)A + (size_t)(m0 + ml) * KPAD + q * 8;
  constexpr int NC2 = KPAD / 64;
  for (int c2 = 0; c2 < NC2; c2++) {
    #pragma unroll
    for (int i0 = 0; i0 < 1024; i0 += 256) {
      int i = i0 + tid;
      size_t g = ((size_t)c2 * 1024 + i) * 8;
      *(uint4*)(&Bs[0][i * 8]) = *(const uint4*)(WfL + g);
      *(uint4*)(&Bs[1][i * 8]) = *(const uint4*)(WfR + g);
    }
    __syncthreads();
    #pragma unroll
    for (int sub = 0; sub < 2; sub++) {
      f16x8 a = *(const f16x8*)(ar0 + c2 * 64 + sub * 32);
      #pragma unroll
      for (int t = 0; t < 8; t++) {
        int idx = (sub * 512 + t * 64 + lane) * 8;
        f16x8 bL = *(const f16x8*)(&Bs[0][idx]);
        f16x8 bR = *(const f16x8*)(&Bs[1][idx]);
        accL[t] = __builtin_amdgcn_mfma_f32_16x16x32_f16(a, bL, accL[t], 0, 0, 0);
        accR[t] = __builtin_amdgcn_mfma_f32_16x16x32_f16(a, bR, accR[t], 0, 0, 0);
      }
    }
    __syncthreads();
  }
  __syncthreads();
  if (!active) return;
  __half* eb = (__half*)&Bs[0][0] + wv * 2048;  // 16 rows x 128 cols fp16
  const int srow = q * 4;
  const int rrow0 = lane >> 4;
  const int rcol = (lane & 15) * 8;
  // ---- L ----
  #pragma unroll
  for (int t = 0; t < 8; t++) {
    int n = t * 16 + ml;
    float bL = bl_[n];
    #pragma unroll
    for (int r = 0; r < 4; r++)
      eb[(srow + r) * 128 + n] = __float2half(accL[t][r] + bL);
  }
  #pragma unroll
  for (int pp = 0; pp < 4; pp++) {
    uint4 v = *(const uint4*)(eb + pp * 512 + lane * 8);
    *(uint4*)(outl + (size_t)(m0 + pp * 4 + rrow0) * 128 + rcol) = v;
  }
  // ---- R ----
  #pragma unroll
  for (int t = 0; t < 8; t++) {
    int n = t * 16 + ml;
    float bR = br_[n];
    #pragma unroll
    for (int r = 0; r < 4; r++)
      eb[(srow + r) * 128 + n] = __float2half(accR[t][r] + bR);
  }
  #pragma unroll
  for (int pp = 0; pp < 4; pp++) {
    uint4 v = *(const uint4*)(eb + pp * 512 + lane * 8);
    *(uint4*)(outr + (size_t)(m0 + pp * 4 + rrow0) * 128 + rcol) = v;
  }
}

// ---------------- GATv2 edge pass: 16 lanes/node (4 nodes/wave) -------------
// Depth-2 software pipeline on the node loop: next group's indptr + xr row
// issue before the current group's edge processing, hiding their latency.
// 8 ch/lane gathers (dwordx4); 4-step quarter-wave reductions; T12 row 255
// = 0 for invalid lock-step slots. Plain-sum softmax (logits O(0.3)).
// Never use unvalidated scode data as an address.
__global__ __launch_bounds__(256) void k_gat(const __half* __restrict__ xl,
                                             const __half* __restrict__ xr,
                                             const int* __restrict__ indptr,
                                             const int4* __restrict__ scode,
                                             const __half* __restrict__ tabs,
                                             const float* __restrict__ att,
                                             const float* __restrict__ bias,
                                             __half* __restrict__ hout) {
  int wid = (blockIdx.x * 256 + threadIdx.x) >> 6;
  int nw = (gridDim.x * 256) >> 6;
  int lane = threadIdx.x & 63;
  int q4 = lane >> 4;            // quarter (node within wave)
  int c = (lane & 15) * 8;       // 8 channels per lane
  const __half* T12 = tabs;      // 256 x 128 fp16
  uint4 vu = *(const uint4*)(tabs + 256 * 128 + c);
  h2 v4[4] = {*reinterpret_cast<h2*>(&vu.x), *reinterpret_cast<h2*>(&vu.y),
              *reinterpret_cast<h2*>(&vu.z), *reinterpret_cast<h2*>(&vu.w)};
  float4 af0 = *(const float4*)(att + c);
  float4 af1 = *(const float4*)(att + c + 4);
  h2 a4[4] = {{(_Float16)af0.x, (_Float16)af0.y}, {(_Float16)af0.z, (_Float16)af0.w},
              {(_Float16)af1.x, (_Float16)af1.y}, {(_Float16)af1.z, (_Float16)af1.w}};
  float bb[8];
  {
    float4 b0 = *(const float4*)(bias + c);
    float4 b1 = *(const float4*)(bias + c + 4);
    bb[0] = b0.x; bb[1] = b0.y; bb[2] = b0.z; bb[3] = b0.w;
    bb[4] = b1.x; bb[5] = b1.y; bb[6] = b1.z; bb[7] = b1.w;
  }
  const h2 z2 = {(_Float16)0.f, (_Float16)0.f};
  const h2 k2 = {(_Float16)0.2f, (_Float16)0.2f};
  wid = __builtin_amdgcn_readfirstlane(wid);
  const int stride = nw * 4;
  int nb = wid * 4;
  if (nb >= N_NODES) return;
  int n = nb + q4;  // N_NODES % 4 == 0 -> always valid
  int bg = indptr[n], en = indptr[n + 1];
  uint4 xru = *(const uint4*)(xr + (size_t)n * 128 + c);
  while (true) {
    // ---- prefetch next node-group's head state (latency hidden by edges) --
    int nb2 = nb + stride;
    bool has2 = (nb2 < N_NODES);
    int n2 = has2 ? nb2 + q4 : n;          // clamp to valid address
    int bg2 = indptr[n2];
    int en2 = indptr[n2 + 1];
    uint4 xru2 = *(const uint4*)(xr + (size_t)n2 * 128 + c);
    // ---- process node n ----
    int beg = bg, end1 = en - 1;           // end1 = self-loop slot
    int last = (end1 > beg) ? end1 - 1 : beg;  // clamp (may be unwritten!)
    h2 xrv[4] = {*reinterpret_cast<h2*>(&xru.x), *reinterpret_cast<h2*>(&xru.y),
                 *reinterpret_cast<h2*>(&xru.z), *reinterpret_cast<h2*>(&xru.w)};
    float denom = 0.f;
    float acc[8] = {0.f, 0.f, 0.f, 0.f, 0.f, 0.f, 0.f, 0.f};
    h2 els[4] = {z2, z2, z2, z2};
    int my_it = (end1 - beg + 3) >> 2;
    int m1 = my_it, m2;
    m2 = __shfl_xor(m1, 16, 64); m1 = m1 > m2 ? m1 : m2;
    m2 = __shfl_xor(m1, 32, 64); m1 = m1 > m2 ? m1 : m2;
    int iters = m1;  // wave-uniform
    for (int it = 0; it < iters; it++) {
      int j = beg + it * 4;
      int4 sc4[4]; h2 xlv[4][4]; float tt[4];
      bool val[4];
      #pragma unroll
      for (int u = 0; u < 4; u++) {
        val[u] = (j + u < end1);  // uniform within quarter
        int jj = val[u] ? j + u : last;
        sc4[u] = scode[jj];
      }
      #pragma unroll
      for (int u = 0; u < 4; u++) {
        int s = val[u] ? sc4[u].x : n;  // NEVER use poison as an address
        uint4 lv = *(const uint4*)(xl + (size_t)s * 128 + c);
        xlv[u][0] = *reinterpret_cast<h2*>(&lv.x);
        xlv[u][1] = *reinterpret_cast<h2*>(&lv.y);
        xlv[u][2] = *reinterpret_cast<h2*>(&lv.z);
        xlv[u][3] = *reinterpret_cast<h2*>(&lv.w);
      }
      #pragma unroll
      for (int u = 0; u < 4; u++) {
        int meta = val[u] ? (sc4[u].y & 255) : 255;  // row 255 = zeros
        float ec = val[u] ? __int_as_float(sc4[u].z) : 0.f;
        uint4 tv = *(const uint4*)(T12 + (size_t)meta * 128 + c);
        h2 t4[4] = {*reinterpret_cast<h2*>(&tv.x), *reinterpret_cast<h2*>(&tv.y),
                    *reinterpret_cast<h2*>(&tv.z), *reinterpret_cast<h2*>(&tv.w)};
        _Float16 eh = (_Float16)ec;
        h2 eh2 = {eh, eh};
        h2 d = z2;
        #pragma unroll
        for (int k = 0; k < 4; k++) {
          h2 el = eh2 * v4[k] + t4[k];
          h2 m = xlv[u][k] + xrv[k] + el;
          h2 l = __builtin_elementwise_max(m, z2) + k2 * __builtin_elementwise_min(m, z2);
          d += l * a4[k];
          els[k] += el;  // el=0 for invalid slots — no mask
        }
        tt[u] = (float)d[0] + (float)d[1];
      }
      // 4 independent quarter-wave reduction chains, 4 steps
      #pragma unroll
      for (int off = 1; off < 16; off <<= 1) {
        tt[0] += __shfl_xor(tt[0], off, 64);
        tt[1] += __shfl_xor(tt[1], off, 64);
        tt[2] += __shfl_xor(tt[2], off, 64);
        tt[3] += __shfl_xor(tt[3], off, 64);
      }
      #pragma unroll
      for (int u = 0; u < 4; u++) {
        float ex = val[u] ? __expf(tt[u]) : 0.f;
        denom += ex;
        #pragma unroll
        for (int k = 0; k < 4; k++) {
          acc[2 * k]     += ex * (float)xlv[u][k][0];
          acc[2 * k + 1] += ex * (float)xlv[u][k][1];
        }
      }
    }
    // self-loop (always present, processed last) — fp32 path
    int cntn = end1 - beg;
    float inv_cnt = 1.0f / (float)(cntn > 0 ? cntn : 1);
    uint4 xnu = *(const uint4*)(xl + (size_t)n * 128 + c);
    h2 xn[4] = {*reinterpret_cast<h2*>(&xnu.x), *reinterpret_cast<h2*>(&xnu.y),
                *reinterpret_cast<h2*>(&xnu.z), *reinterpret_cast<h2*>(&xnu.w)};
    float afv[8] = {af0.x, af0.y, af0.z, af0.w, af1.x, af1.y, af1.z, af1.w};
    float ts = 0.f;
    float xnf[8];
    #pragma unroll
    for (int k = 0; k < 4; k++) {
      #pragma unroll
      for (int hh = 0; hh < 2; hh++) {
        int i = 2 * k + hh;
        xnf[i] = (float)xn[k][hh];
        float m = xnf[i] + (float)xrv[k][hh] + (float)els[k][hh] * inv_cnt;
        float l = m > 0.f ? m : 0.2f * m;
        ts += l * afv[i];
      }
    }
    #pragma unroll
    for (int off = 1; off < 16; off <<= 1) ts += __shfl_xor(ts, off, 64);
    float ex = __expf(ts);
    denom += ex;
    #pragma unroll
    for (int i = 0; i < 8; i++) acc[i] += ex * xnf[i];
    float invd = 1.0f / denom;
    h2 p[4];
    #pragma unroll
    for (int k = 0; k < 4; k++) {
      float o0 = acc[2 * k] * invd + bb[2 * k];
      float o1 = acc[2 * k + 1] * invd + bb[2 * k + 1];
      o0 = o0 > 0.f ? o0 : 0.f;
      o1 = o1 > 0.f ? o1 : 0.f;
      p[k] = (h2){(_Float16)o0, (_Float16)o1};
    }
    uint4 st = make_uint4(*reinterpret_cast<unsigned*>(&p[0]),
                          *reinterpret_cast<unsigned*>(&p[1]),
                          *reinterpret_cast<unsigned*>(&p[2]),
                          *reinterpret_cast<unsigned*>(&p[3]));
    *(uint4*)(hout + (size_t)n * 128 + c) = st;
    // ---- advance pipeline ----
    if (!has2) break;
    nb = nb2; n = n2; bg = bg2; en = en2; xru = xru2;
  }
}

// ---------------- readout: global max pool over 20 contiguous nodes --------
__global__ void k_readout(const __half* __restrict__ h, float* __restrict__ out) {
  int wid = (blockIdx.x * blockDim.x + threadIdx.x) >> 6;
  int lane = threadIdx.x & 63;
  if (wid >= N_GRAPHS) return;
  int c = lane * 2;
  float m0 = -1e30f, m1 = -1e30f;
  for (int i = 0; i < NPG; i++) {
    unsigned v = *(const unsigned*)(h + ((size_t)(wid * NPG + i)) * 128 + c);
    h2 f = *reinterpret_cast<h2*>(&v);
    m0 = fmaxf(m0, (float)f[0]);
    m1 = fmaxf(m1, (float)f[1]);
  }
  float2 o; o.x = m0; o.y = m1;
  *(float2*)(out + (size_t)wid * 128 + c) = o;
}

extern "C" void kernel_launch(void* const* d_in, const int* in_sizes, int n_in,
                              void* d_out, int out_size, void* d_ws, size_t ws_size,
                              hipStream_t stream) {
  (void)in_sizes; (void)n_in; (void)out_size; (void)ws_size;
  const float* x        = (const float*)d_in[0];
  const int*   eindex   = (const int*)d_in[1];
  const float* eattr    = (const float*)d_in[2];
  const float* atom_emb = (const float*)d_in[4];
  const float* bond_emb = (const float*)d_in[5];
  const float* bool_emb = (const float*)d_in[6];
  const float* Wn   = (const float*)d_in[7];
  const float* bn   = (const float*)d_in[8];
  const float* We   = (const float*)d_in[9];
  const float* be   = (const float*)d_in[10];
  const float* Wl1  = (const float*)d_in[11];
  const float* bl1  = (const float*)d_in[12];
  const float* Wr1  = (const float*)d_in[13];
  const float* br1  = (const float*)d_in[14];
  const float* Wedge1 = (const float*)d_in[15];
  const float* att1 = (const float*)d_in[16];
  const float* bias1 = (const float*)d_in[17];
  const float* Wl2  = (const float*)d_in[18];
  const float* bl2  = (const float*)d_in[19];
  const float* Wr2  = (const float*)d_in[20];
  const float* br2  = (const float*)d_in[21];
  const float* Wedge2 = (const float*)d_in[22];
  const float* att2 = (const float*)d_in[23];
  const float* bias2 = (const float*)d_in[24];

  const int* srcA = eindex;
  const int* dstA = eindex + N_EDGES;

  char* p = (char*)d_ws;
  auto alloc = [&](size_t bytes) {
    char* r = p;
    p += (bytes + 255) & ~(size_t)255;
    return r;
  };
  __half* h0     = (__half*)alloc((size_t)N_NODES * 64 * 2);
  __half* h      = (__half*)alloc((size_t)N_NODES * 128 * 2);
  __half* xl     = (__half*)alloc((size_t)N_NODES * 128 * 2);
  __half* xrb    = (__half*)alloc((size_t)N_NODES * 128 * 2);
  int*    cnt    = (int*)alloc((size_t)N_NODES * 4);
  int*    indptr = (int*)alloc((size_t)(N_NODES + 1) * 4);
  int*    cursor = (int*)alloc((size_t)N_NODES * 4);
  int4*   scode  = (int4*)alloc((size_t)(N_EDGES + N_NODES) * 16);
  __half* tabs   = (__half*)alloc((size_t)2 * TAB_STRIDE * 2);
  unsigned short* wfrag = (unsigned short*)alloc((size_t)(2 * F1 + 2 * F2) * 2);
  int*    bsum   = (int*)alloc((size_t)SCAN_NB * 4);

  (void)hipMemsetAsync(cnt, 0, (size_t)N_NODES * 4, stream);

  // fused prologue: encode | hist | tabs | prep
  k_prologue<<<NB_ENC + NB_HIST + 1 + 24, 256, 0, stream>>>(
      x, atom_emb, bool_emb, Wn, bn, h0, dstA, cnt,
      Wedge1, Wedge2, bond_emb, We, be, tabs,
      Wl1, Wr1, Wl2, Wr2, wfrag);
  k_scan1<<<SCAN_NB, 256, 0, stream>>>(cnt, bsum);
  k_scan3<<<SCAN_NB, 256, 0, stream>>>(cnt, bsum, indptr, cursor);
  k_fill<<<(N_EDGES + 255) / 256, 256, 0, stream>>>(srcA, dstA, eattr, cursor, scode);

  const unsigned short* f_l1 = wfrag;
  const unsigned short* f_r1 = wfrag + F1;
  const unsigned short* f_l2 = wfrag + 2 * F1;
  const unsigned short* f_r2 = wfrag + 2 * F1 + F2;

  const int GB2 = (N_NODES / 16 + 3) / 4;  // 1563 blocks of 4 waves

  // layer 1 (K=52 zero-padded to 64)
  k_gemm2m<64><<<GB2, 256, 0, stream>>>(h0, f_l1, f_r1, bl1, br1, xl, xrb);
  k_gat<<<2048, 256, 0, stream>>>(xl, xrb, indptr, scode, tabs, att1, bias1, h);

  // layer 2 (K=128)
  k_gemm2m<128><<<GB2, 256, 0, stream>>>(h, f_l2, f_r2, bl2, br2, xl, xrb);
  k_gat<<<2048, 256, 0, stream>>>(xl, xrb, indptr, scode, tabs + TAB_STRIDE, att2, bias2, h);

  // layer 3 (shared weights with layer 2)
  k_gemm2m<128><<<GB2, 256, 0, stream>>>(h, f_l2, f_r2, bl2, br2, xl, xrb);
  k_gat<<<2048, 256, 0, stream>>>(xl, xrb, indptr, scode, tabs + TAB_STRIDE, att2, bias2, h);

  k_readout<<<(N_GRAPHS * 64 + 255) / 256, 256, 0, stream>>>(h, (float*)d_out);
}